// Round 1
// baseline (2987.835 us; speedup 1.0000x reference)
//
#include <hip/hip_runtime.h>
#include <cmath>
#include <cstdint>
#include <cstddef>
#include <type_traits>

typedef unsigned short bf16_t;

__device__ __forceinline__ float bf2f(bf16_t b){
  unsigned int u = ((unsigned int)b) << 16;
  return __uint_as_float(u);
}
__device__ __forceinline__ bf16_t f2bf(float f){
  unsigned int u = __float_as_uint(f);
  unsigned int r = (u + 0x7fffu + ((u >> 16) & 1u)) >> 16;  // RNE
  return (bf16_t)r;
}
__device__ __forceinline__ float sigf(float x){ return 1.0f / (1.0f + expf(-x)); }

// ---------------- elementwise add ----------------
__global__ void vadd_kernel(const float* __restrict__ a, const float* __restrict__ b,
                            float* __restrict__ o, int n){
  int i = blockIdx.x * blockDim.x + threadIdx.x;
  if (i < n) o[i] = a[i] + b[i];
}

// ---------------- transpose: WT[c*R+r] = W[r*C+c], W is RxC ----------------
__global__ void transpose_kernel(const float* __restrict__ W, float* __restrict__ WT, int R, int C){
  int i = blockIdx.x * blockDim.x + threadIdx.x;
  if (i < R * C){ int r = i / C, c = i % C; WT[(size_t)c * R + r] = W[i]; }
}

// ---------------- data batchnorm: x(N,C,T,V,M) -> h1[(nm*C+c)*T+t][V] ----------------
__global__ void data_bn_kernel(const float* __restrict__ x, const float* __restrict__ g,
                               const float* __restrict__ bb, float* __restrict__ h1,
                               int N, int C, int T, int V, int M){
  int ch = blockIdx.x;             // (m*V + v)*C + c
  int m = ch / (V * C);
  int v = (ch / C) % V;
  int c = ch % C;
  int tid = threadIdx.x;
  int cnt = N * T;
  float s = 0.f, s2 = 0.f;
  for (int i = tid; i < cnt; i += 64){
    int n = i / T, t = i % T;
    float val = x[(((size_t)(n * C + c) * T + t) * V + v) * M + m];
    s += val; s2 += val * val;
  }
  for (int off = 32; off; off >>= 1){ s += __shfl_down(s, off); s2 += __shfl_down(s2, off); }
  s = __shfl(s, 0); s2 = __shfl(s2, 0);
  float mean = s / cnt;
  float rstd = rsqrtf(s2 / cnt - mean * mean + 1e-5f);
  float gg = g[ch], bo = bb[ch];
  for (int i = tid; i < cnt; i += 64){
    int n = i / T, t = i % T;
    float val = x[(((size_t)(n * C + c) * T + t) * V + v) * M + m];
    float y = (val - mean) * rstd * gg + bo;
    h1[((size_t)((n * M + m) * C + c) * T + t) * V + v] = y;
  }
}

// ---------------- support: sup[row][w] = sum_u A[w][u]*hin[row][u], row=(nm*C+c)*T+t ----------------
__global__ void support1_kernel(const float* __restrict__ A, const float* __restrict__ hin,
                                float* __restrict__ sup, int total){
  int idx = blockIdx.x * blockDim.x + threadIdx.x;
  if (idx >= total) return;
  int w = idx % 325;
  int rest = idx / 325;
  const float* row = hin + (size_t)rest * 25;
  const float* ar = A + w * 25;
  float acc = 0.f;
  #pragma unroll
  for (int u = 0; u < 25; ++u) acc += ar[u] * row[u];
  sup[idx] = acc;
}

// ---------------- gcn1 output: y1[((nm*T+t)*25+v)*96+o] ----------------
__global__ void gcn1_out_kernel(const float* __restrict__ sup, const float* __restrict__ W1,
                                const float* __restrict__ b1, float* __restrict__ y1, int NM, int T){
  int idx = blockIdx.x * blockDim.x + threadIdx.x;
  int total = NM * T * 25 * 96;
  if (idx >= total) return;
  int o = idx % 96;
  int v = (idx / 96) % 25;
  int t = (idx / (96 * 25)) % T;
  int nm = idx / (96 * 25 * T);
  float acc = b1[o];
  #pragma unroll
  for (int k = 0; k < 13; ++k)
    #pragma unroll
    for (int c = 0; c < 3; ++c)
      acc += W1[o * 39 + k * 3 + c] * sup[(size_t)((nm * 3 + c) * T + t) * 325 + k * 25 + v];
  y1[idx] = acc;
}

// ---------------- per-column stats of mat[R][Cc] ----------------
__global__ void colstats_kernel(const float* __restrict__ mat, int R, int Cc,
                                float* __restrict__ mean, float* __restrict__ rstd){
  int col = blockIdx.x;
  float s = 0.f, s2 = 0.f;
  for (int r = threadIdx.x; r < R; r += blockDim.x){
    float v = mat[(size_t)r * Cc + col]; s += v; s2 += v * v;
  }
  __shared__ float sa[4], sb[4];
  int lane = threadIdx.x & 63, wid = threadIdx.x >> 6;
  for (int off = 32; off; off >>= 1){ s += __shfl_down(s, off); s2 += __shfl_down(s2, off); }
  if (lane == 0){ sa[wid] = s; sb[wid] = s2; }
  __syncthreads();
  if (threadIdx.x == 0){
    s = sa[0] + sa[1] + sa[2] + sa[3];
    s2 = sb[0] + sb[1] + sb[2] + sb[3];
    float m = s / R;
    mean[col] = m;
    rstd[col] = rsqrtf(s2 / R - m * m + 1e-5f);
  }
}

// ---------------- bn + relu + transpose to sequence layout ----------------
__global__ void bn_relu_seq_kernel(const float* __restrict__ ymat, const float* __restrict__ mean,
                                   const float* __restrict__ rstd, const float* __restrict__ g,
                                   const float* __restrict__ bb, float* __restrict__ xseq,
                                   int NM, int T, int H){
  int idx = blockIdx.x * blockDim.x + threadIdx.x;
  int total = NM * T * 25 * H;
  if (idx >= total) return;
  int o = idx % H;
  int v = (idx / H) % 25;
  int t = (idx / (H * 25)) % T;
  int nm = idx / (H * 25 * T);
  float val = (ymat[idx] - mean[o]) * rstd[o] * g[o] + bb[o];
  val = fmaxf(val, 0.f);
  int b = nm * 25 + v;
  xseq[((size_t)b * T + t) * H + o] = val;
}

// ---------------- log-signature features (x_start, inc, levy) -> bf16 rows ----------------
struct SegTable { int st[50]; int en[50]; };

__global__ void feats_kernel(const float* __restrict__ xseq, bf16_t* __restrict__ feats,
                             SegTable segs, int T, int d, int S, int L, int pairs){
  __shared__ float pts[4][192];
  int bs = blockIdx.x;
  int b = bs / S, s = bs % S;
  int st = segs.st[s], en = segs.en[s];
  int nt = blockDim.x, tid = threadIdx.x;
  for (int l = 0; l < L; ++l){
    int t = st + l; if (t > en) t = en;
    for (int i = tid; i < d; i += nt) pts[l][i] = xseq[((size_t)b * T + t) * d + i];
  }
  __syncthreads();
  size_t rowlen = (size_t)(2 * d + pairs);
  bf16_t* frow = feats + (size_t)bs * rowlen;
  for (int i = tid; i < d; i += nt){
    frow[i] = f2bf(pts[0][i]);
    frow[d + i] = f2bf(pts[L - 1][i] - pts[0][i]);
  }
  for (int i = 0; i < d - 1; ++i){
    int base = 2 * d + i * (d - 1) - (i * (i - 1)) / 2;
    float reli[3], dxi[3];
    #pragma unroll
    for (int l = 1; l <= 2; ++l){
      if (l <= L - 2){
        reli[l] = pts[l][i] - pts[0][i];
        dxi[l]  = pts[l + 1][i] - pts[l][i];
      } else { reli[l] = 0.f; dxi[l] = 0.f; }
    }
    int rl = d - 1 - i;
    for (int jj = tid; jj < rl; jj += nt){
      int j = i + 1 + jj;
      float acc = 0.f;
      for (int l = 1; l <= L - 2; ++l){
        float relj = pts[l][j] - pts[0][j];
        float dxj  = pts[l + 1][j] - pts[l][j];
        acc += reli[l] * dxj - relj * dxi[l];
      }
      frow[base + jj] = f2bf(0.5f * acc);
    }
  }
}

// ---------------- tiled GEMM: C[M][N] = A[M][K] * B[N][K]^T + bias ----------------
template <typename TA>
__global__ __launch_bounds__(256)
void gemm_nt_kernel(const TA* __restrict__ A, const float* __restrict__ B,
                    const float* __restrict__ bias, float* __restrict__ C,
                    int M, int N, int K){
  __shared__ float As[32][68];
  __shared__ float Bs[32][68];
  const int tid = threadIdx.x;
  const int tx = tid & 15, ty = tid >> 4;
  const int bm = blockIdx.x * 64, bn = blockIdx.y * 64;
  const int lr = tid >> 2;          // 0..63 row in tile
  const int lc = (tid & 3) * 8;     // 0,8,16,24
  float acc[4][4] = {};
  for (int k0 = 0; k0 < K; k0 += 32){
    {
      int row = bm + lr;
      float va[8];
      if (row < M && (k0 + lc + 8) <= K){
        if constexpr (std::is_same<TA, bf16_t>::value){
          const uint4 u = *reinterpret_cast<const uint4*>(A + (size_t)row * K + k0 + lc);
          va[0] = bf2f((bf16_t)(u.x & 0xffff)); va[1] = bf2f((bf16_t)(u.x >> 16));
          va[2] = bf2f((bf16_t)(u.y & 0xffff)); va[3] = bf2f((bf16_t)(u.y >> 16));
          va[4] = bf2f((bf16_t)(u.z & 0xffff)); va[5] = bf2f((bf16_t)(u.z >> 16));
          va[6] = bf2f((bf16_t)(u.w & 0xffff)); va[7] = bf2f((bf16_t)(u.w >> 16));
        } else {
          const float4* p = reinterpret_cast<const float4*>(A + (size_t)row * K + k0 + lc);
          float4 x0 = p[0], x1 = p[1];
          va[0] = x0.x; va[1] = x0.y; va[2] = x0.z; va[3] = x0.w;
          va[4] = x1.x; va[5] = x1.y; va[6] = x1.z; va[7] = x1.w;
        }
      } else {
        #pragma unroll
        for (int j = 0; j < 8; ++j){
          int k = k0 + lc + j;
          float vv = 0.f;
          if (row < M && k < K){
            if constexpr (std::is_same<TA, bf16_t>::value) vv = bf2f(A[(size_t)row * K + k]);
            else vv = (float)A[(size_t)row * K + k];
          }
          va[j] = vv;
        }
      }
      #pragma unroll
      for (int j = 0; j < 8; ++j) As[lc + j][lr] = va[j];
    }
    {
      int row = bn + lr;
      float vb[8];
      if (row < N && (k0 + lc + 8) <= K){
        const float4* p = reinterpret_cast<const float4*>(B + (size_t)row * K + k0 + lc);
        float4 x0 = p[0], x1 = p[1];
        vb[0] = x0.x; vb[1] = x0.y; vb[2] = x0.z; vb[3] = x0.w;
        vb[4] = x1.x; vb[5] = x1.y; vb[6] = x1.z; vb[7] = x1.w;
      } else {
        #pragma unroll
        for (int j = 0; j < 8; ++j){
          int k = k0 + lc + j;
          vb[j] = (row < N && k < K) ? B[(size_t)row * K + k] : 0.f;
        }
      }
      #pragma unroll
      for (int j = 0; j < 8; ++j) Bs[lc + j][lr] = vb[j];
    }
    __syncthreads();
    #pragma unroll
    for (int kk = 0; kk < 32; ++kk){
      const float4 a = *reinterpret_cast<const float4*>(&As[kk][ty * 4]);
      const float4 b = *reinterpret_cast<const float4*>(&Bs[kk][tx * 4]);
      acc[0][0] += a.x * b.x; acc[0][1] += a.x * b.y; acc[0][2] += a.x * b.z; acc[0][3] += a.x * b.w;
      acc[1][0] += a.y * b.x; acc[1][1] += a.y * b.y; acc[1][2] += a.y * b.z; acc[1][3] += a.y * b.w;
      acc[2][0] += a.z * b.x; acc[2][1] += a.z * b.y; acc[2][2] += a.z * b.z; acc[2][3] += a.z * b.w;
      acc[3][0] += a.w * b.x; acc[3][1] += a.w * b.y; acc[3][2] += a.w * b.z; acc[3][3] += a.w * b.w;
    }
    __syncthreads();
  }
  #pragma unroll
  for (int i = 0; i < 4; ++i){
    int row = bm + ty * 4 + i;
    if (row >= M) continue;
    #pragma unroll
    for (int j = 0; j < 4; ++j){
      int col = bn + tx * 4 + j;
      if (col >= N) continue;
      float r = acc[i][j];
      if (bias) r += bias[col];
      C[(size_t)row * N + col] = r;
    }
  }
}

// ---------------- persistent per-sequence LSTM ----------------
__global__ void lstm_kernel(const float* __restrict__ xp, const float* __restrict__ WhhT,
                            float* __restrict__ out, int S, int H){
  extern __shared__ float sm[];
  float* hv = sm;          // H
  float* cv = sm + H;      // H
  float* gv = sm + 2 * H;  // 4H
  int b = blockIdx.x;
  int t = threadIdx.x;     // < 4H
  int H4 = 4 * H;
  if (t < H){ hv[t] = 0.f; cv[t] = 0.f; }
  __syncthreads();
  for (int s = 0; s < S; ++s){
    float acc = xp[((size_t)b * S + s) * H4 + t];
    for (int j = 0; j < H; j += 4){
      acc += WhhT[(size_t)j * H4 + t]       * hv[j]
           + WhhT[(size_t)(j + 1) * H4 + t] * hv[j + 1]
           + WhhT[(size_t)(j + 2) * H4 + t] * hv[j + 2]
           + WhhT[(size_t)(j + 3) * H4 + t] * hv[j + 3];
    }
    gv[t] = acc;
    __syncthreads();
    if (t < H){
      float ig = sigf(gv[t]);
      float fg = sigf(gv[H + t]);
      float gg = tanhf(gv[2 * H + t]);
      float og = sigf(gv[3 * H + t]);
      float cc = fg * cv[t] + ig * gg;
      cv[t] = cc;
      float hh = og * tanhf(cc);
      hv[t] = hh;
      out[((size_t)b * S + s) * H + t] = hh;
    }
    __syncthreads();
  }
}

// ---------------- per-segment (channel=s) stats over (b,h) ----------------
__global__ void segstats_kernel(const float* __restrict__ lout, int B, int S, int H,
                                float* __restrict__ mean, float* __restrict__ rstd){
  int s = blockIdx.x;
  float sum = 0.f, sum2 = 0.f;
  int cnt = B * H;
  for (int i = threadIdx.x; i < cnt; i += blockDim.x){
    int b = i / H, hh = i % H;
    float v = lout[((size_t)b * S + s) * H + hh];
    sum += v; sum2 += v * v;
  }
  __shared__ float sa[4], sb[4];
  int lane = threadIdx.x & 63, wid = threadIdx.x >> 6;
  for (int off = 32; off; off >>= 1){ sum += __shfl_down(sum, off); sum2 += __shfl_down(sum2, off); }
  if (lane == 0){ sa[wid] = sum; sb[wid] = sum2; }
  __syncthreads();
  if (threadIdx.x == 0){
    sum = sa[0] + sa[1] + sa[2] + sa[3];
    sum2 = sb[0] + sb[1] + sb[2] + sb[3];
    float m = sum / cnt;
    mean[s] = m;
    rstd[s] = rsqrtf(sum2 / cnt - m * m + 1e-5f);
  }
}

// ---------------- bnseg apply + transpose to gcn2 input layout ----------------
__global__ void bnseg_to_g2in_kernel(const float* __restrict__ lout, const float* __restrict__ mean,
                                     const float* __restrict__ rstd, const float* __restrict__ g,
                                     const float* __restrict__ bb, float* __restrict__ g2in,
                                     int B, int S, int H){
  int idx = blockIdx.x * blockDim.x + threadIdx.x;
  int total = B * S * H;
  if (idx >= total) return;
  int hh = idx % H;
  int s = (idx / H) % S;
  int b = idx / (H * S);
  float val = (lout[idx] - mean[s]) * rstd[s] * g[s] + bb[s];
  int nm = b / 25, v = b % 25;
  g2in[((size_t)((nm * H + hh) * S) + s) * 25 + v] = val;
}

// ---------------- support2 -> A2mat[(nm*S+s)*25+v][k*96+c] ----------------
__global__ void support2_kernel(const float* __restrict__ A, const float* __restrict__ g2in,
                                float* __restrict__ A2mat, int NM, int C1, int S){
  int idx = blockIdx.x * blockDim.x + threadIdx.x;
  int total = NM * C1 * S * 325;
  if (idx >= total) return;
  int w = idx % 325;
  int s = (idx / 325) % S;
  int c = (idx / (325 * S)) % C1;
  int nm = idx / (325 * S * C1);
  const float* row = g2in + ((size_t)((nm * C1 + c) * S) + s) * 25;
  const float* ar = A + w * 25;
  float acc = 0.f;
  #pragma unroll
  for (int u = 0; u < 25; ++u) acc += ar[u] * row[u];
  int k = w / 25, v = w % 25;
  A2mat[((size_t)((nm * S + s) * 25 + v)) * 1248 + k * C1 + c] = acc;
}

// ---------------- bnseg2 + global pool ----------------
__global__ void pool_kernel(const float* __restrict__ lout2, const float* __restrict__ mean,
                            const float* __restrict__ rstd, const float* __restrict__ g,
                            const float* __restrict__ bb, float* __restrict__ pooled,
                            int S, int H){
  int n = blockIdx.x / H;
  int o = blockIdx.x % H;
  float sum = 0.f;
  int cnt = 2 * 25 * S;
  for (int i = threadIdx.x; i < cnt; i += 64){
    int m = i / (25 * S);
    int r = i % (25 * S);
    int v = r / S;
    int s = r % S;
    int b = (n * 2 + m) * 25 + v;
    float val = lout2[((size_t)b * S + s) * H + o];
    val = (val - mean[s]) * rstd[s] * g[s] + bb[s];
    sum += val;
  }
  for (int off = 32; off; off >>= 1) sum += __shfl_down(sum, off);
  if (threadIdx.x == 0) pooled[n * H + o] = sum / cnt;
}

// ---------------- final FC ----------------
__global__ void fc_kernel(const float* __restrict__ pooled, const float* __restrict__ fcW,
                          const float* __restrict__ fcb, float* __restrict__ outp){
  int idx = blockIdx.x * blockDim.x + threadIdx.x;
  if (idx >= 120) return;
  int n = idx / 60, cls = idx % 60;
  float acc = fcb[cls];
  for (int o = 0; o < 192; ++o) acc += pooled[n * 192 + o] * fcW[cls * 192 + o];
  outp[idx] = acc;
}

// ---------------- host: replicate np.linspace + python round (ties-to-even) ----------------
static void make_segs(int T, int S, SegTable& tab, int& L){
  double step = (double)(T - 1) / (double)S;
  long long tv[51];
  for (int i = 0; i <= S; ++i){
    double v = 1.0 + step * (double)i;   // matches numpy: arange(i)*step + start
    tv[i] = llrint(v);                   // FE_TONEAREST == ties-to-even == python round
  }
  L = 0;
  for (int s = 0; s < S; ++s){
    tab.st[s] = (int)tv[s] - 1;
    tab.en[s] = (int)tv[s + 1] - 1;
    int len = tab.en[s] - tab.st[s] + 1;
    if (len > L) L = len;
  }
  for (int s = S; s < 50; ++s){ tab.st[s] = 0; tab.en[s] = 0; }
  if (L > 4) L = 4;  // never expected; pts LDS holds 4 rows
}

extern "C" void kernel_launch(void* const* d_in, const int* in_sizes, int n_in,
                              void* d_out, int out_size, void* d_ws, size_t ws_size,
                              hipStream_t stream){
  const float* x         = (const float*)d_in[0];
  const float* data_bn_g = (const float*)d_in[2];
  const float* data_bn_b = (const float*)d_in[3];
  const float* A_powers1 = (const float*)d_in[4];
  const float* A_res1    = (const float*)d_in[5];
  const float* W1        = (const float*)d_in[6];
  const float* b1        = (const float*)d_in[7];
  const float* bn1_g     = (const float*)d_in[8];
  const float* bn1_b     = (const float*)d_in[9];
  const float* Wih1      = (const float*)d_in[10];
  const float* Whh1      = (const float*)d_in[11];
  const float* bih1      = (const float*)d_in[12];
  const float* bhh1      = (const float*)d_in[13];
  const float* bnseg1_g  = (const float*)d_in[14];
  const float* bnseg1_b  = (const float*)d_in[15];
  const float* A_powers2 = (const float*)d_in[16];
  const float* A_res2    = (const float*)d_in[17];
  const float* W2        = (const float*)d_in[18];
  const float* b2        = (const float*)d_in[19];
  const float* bn2_g     = (const float*)d_in[20];
  const float* bn2_b     = (const float*)d_in[21];
  const float* Wih2      = (const float*)d_in[22];
  const float* Whh2      = (const float*)d_in[23];
  const float* bih2      = (const float*)d_in[24];
  const float* bhh2      = (const float*)d_in[25];
  const float* bnseg2_g  = (const float*)d_in[26];
  const float* bnseg2_b  = (const float*)d_in[27];
  const float* fcW       = (const float*)d_in[28];
  const float* fcb       = (const float*)d_in[29];
  float* out = (float*)d_out;

  const int N = 2, C = 3, T = 100, V = 25, M = 2, NM = 4;
  const int K = 13, C1 = 96, C2 = 192;
  const int S1 = 50, S2 = 30;
  const int B = 100;
  const int IN1 = 4752, IN2 = 18720;
  const int P1 = 4560, P2 = 18336;

  size_t off = 0;
  char* base = (char*)d_ws;
  auto alloc = [&](size_t nbytes) -> void* {
    off = (off + 255) & ~(size_t)255;
    void* p = base + off;
    off += nbytes;
    return p;
  };
  float* A1full = (float*)alloc(325 * 25 * 4);
  float* A2full = (float*)alloc(325 * 25 * 4);
  float* h1     = (float*)alloc((size_t)NM * C * T * V * 4);
  float* sup1   = (float*)alloc((size_t)NM * C * T * 325 * 4);
  float* y1mat  = (float*)alloc((size_t)NM * T * V * C1 * 4);
  float* meanb  = (float*)alloc(1024);
  float* rstdb  = (float*)alloc(1024);
  float* xseq1  = (float*)alloc((size_t)B * T * C1 * 4);
  float* xp1    = (float*)alloc((size_t)B * S1 * 4 * C1 * 4);
  float* l1out  = (float*)alloc((size_t)B * S1 * C1 * 4);
  float* g2in   = (float*)alloc((size_t)NM * C1 * S1 * V * 4);
  float* A2mat  = (float*)alloc((size_t)NM * S1 * V * (K * C1) * 4);
  float* y2mat  = (float*)alloc((size_t)NM * S1 * V * C2 * 4);
  float* xseq2  = (float*)alloc((size_t)B * S1 * C2 * 4);
  float* xp2    = (float*)alloc((size_t)B * S2 * 4 * C2 * 4);
  float* l2out  = (float*)alloc((size_t)B * S2 * C2 * 4);
  float* pooled = (float*)alloc(2 * C2 * 4);
  float* bias1  = (float*)alloc(4 * C1 * 4);
  float* bias2  = (float*)alloc(4 * C2 * 4);
  float* WhhT1  = (float*)alloc((size_t)4 * C1 * C1 * 4);
  float* WhhT2  = (float*)alloc((size_t)4 * C2 * C2 * 4);
  // shared big buffer: feats1 (23.76M elems) then feats2 (56.16M elems), bf16
  bf16_t* feats = (bf16_t*)alloc((size_t)B * S2 * IN2 * 2);
  (void)ws_size; (void)in_sizes; (void)n_in; (void)out_size;

  // constant prep
  vadd_kernel<<<(8125 + 255) / 256, 256, 0, stream>>>(A_powers1, A_res1, A1full, 8125);
  vadd_kernel<<<(8125 + 255) / 256, 256, 0, stream>>>(A_powers2, A_res2, A2full, 8125);
  vadd_kernel<<<2, 256, 0, stream>>>(bih1, bhh1, bias1, 4 * C1);
  vadd_kernel<<<3, 256, 0, stream>>>(bih2, bhh2, bias2, 4 * C2);
  transpose_kernel<<<(4 * C1 * C1 + 255) / 256, 256, 0, stream>>>(Whh1, WhhT1, 4 * C1, C1);
  transpose_kernel<<<(4 * C2 * C2 + 255) / 256, 256, 0, stream>>>(Whh2, WhhT2, 4 * C2, C2);

  // stage 0: data BN
  data_bn_kernel<<<M * V * C, 64, 0, stream>>>(x, data_bn_g, data_bn_b, h1, N, C, T, V, M);

  // stage 1: GCN1
  int tot_sup1 = NM * C * T * 325;
  support1_kernel<<<(tot_sup1 + 255) / 256, 256, 0, stream>>>(A1full, h1, sup1, tot_sup1);
  int tot_y1 = NM * T * 25 * C1;
  gcn1_out_kernel<<<(tot_y1 + 255) / 256, 256, 0, stream>>>(sup1, W1, b1, y1mat, NM, T);
  colstats_kernel<<<C1, 256, 0, stream>>>(y1mat, NM * T * 25, C1, meanb, rstdb);
  bn_relu_seq_kernel<<<(tot_y1 + 255) / 256, 256, 0, stream>>>(y1mat, meanb, rstdb, bn1_g, bn1_b,
                                                               xseq1, NM, T, C1);

  // stage 1: logsig-rnn
  SegTable seg1, seg2; int L1, L2;
  make_segs(T, S1, seg1, L1);
  make_segs(S1, S2, seg2, L2);

  feats_kernel<<<B * S1, 256, 0, stream>>>(xseq1, feats, seg1, T, C1, S1, L1, P1);
  {
    dim3 g((B * S1 + 63) / 64, (4 * C1 + 63) / 64);
    gemm_nt_kernel<bf16_t><<<g, 256, 0, stream>>>(feats, Wih1, bias1, xp1, B * S1, 4 * C1, IN1);
  }
  lstm_kernel<<<B, 4 * C1, 6 * C1 * 4, stream>>>(xp1, WhhT1, l1out, S1, C1);
  segstats_kernel<<<S1, 256, 0, stream>>>(l1out, B, S1, C1, meanb, rstdb);
  int tot_bn1 = B * S1 * C1;
  bnseg_to_g2in_kernel<<<(tot_bn1 + 255) / 256, 256, 0, stream>>>(l1out, meanb, rstdb, bnseg1_g,
                                                                  bnseg1_b, g2in, B, S1, C1);

  // stage 2: GCN2
  int tot_sup2 = NM * C1 * S1 * 325;
  support2_kernel<<<(tot_sup2 + 255) / 256, 256, 0, stream>>>(A2full, g2in, A2mat, NM, C1, S1);
  {
    dim3 g((NM * S1 * 25 + 63) / 64, (C2 + 63) / 64);
    gemm_nt_kernel<float><<<g, 256, 0, stream>>>(A2mat, W2, b2, y2mat, NM * S1 * 25, C2, K * C1);
  }
  colstats_kernel<<<C2, 256, 0, stream>>>(y2mat, NM * S1 * 25, C2, meanb, rstdb);
  int tot_y2 = NM * S1 * 25 * C2;
  bn_relu_seq_kernel<<<(tot_y2 + 255) / 256, 256, 0, stream>>>(y2mat, meanb, rstdb, bn2_g, bn2_b,
                                                               xseq2, NM, S1, C2);

  // stage 2: logsig-rnn
  feats_kernel<<<B * S2, 256, 0, stream>>>(xseq2, feats, seg2, S1, C2, S2, L2, P2);
  {
    dim3 g((B * S2 + 63) / 64, (4 * C2 + 63) / 64);
    gemm_nt_kernel<bf16_t><<<g, 256, 0, stream>>>(feats, Wih2, bias2, xp2, B * S2, 4 * C2, IN2);
  }
  lstm_kernel<<<B, 4 * C2, 6 * C2 * 4, stream>>>(xp2, WhhT2, l2out, S2, C2);
  segstats_kernel<<<S2, 256, 0, stream>>>(l2out, B, S2, C2, meanb, rstdb);

  // pool + fc
  pool_kernel<<<2 * C2, 64, 0, stream>>>(l2out, meanb, rstdb, bnseg2_g, bnseg2_b, pooled, S2, C2);
  fc_kernel<<<1, 128, 0, stream>>>(pooled, fcW, fcb, out);
}

// Round 2
// 1549.227 us; speedup vs baseline: 1.9286x; 1.9286x over previous
//
#include <hip/hip_runtime.h>
#include <cmath>
#include <cstdint>
#include <cstddef>
#include <type_traits>

typedef unsigned short bf16_t;
typedef __attribute__((ext_vector_type(8))) short short8;
typedef __attribute__((ext_vector_type(4))) float floatx4;

__device__ __forceinline__ float bf2f(bf16_t b){
  unsigned int u = ((unsigned int)b) << 16;
  return __uint_as_float(u);
}
__device__ __forceinline__ bf16_t f2bf(float f){
  unsigned int u = __float_as_uint(f);
  unsigned int r = (u + 0x7fffu + ((u >> 16) & 1u)) >> 16;  // RNE
  return (bf16_t)r;
}
__device__ __forceinline__ float sigf(float x){ return 1.0f / (1.0f + expf(-x)); }

__device__ __forceinline__ void gload_lds16(const bf16_t* g, bf16_t* lds){
  __builtin_amdgcn_global_load_lds(
      (const __attribute__((address_space(1))) unsigned int*)g,
      (__attribute__((address_space(3))) unsigned int*)lds, 16, 0, 0);
}

// ---------------- elementwise add ----------------
__global__ void vadd_kernel(const float* __restrict__ a, const float* __restrict__ b,
                            float* __restrict__ o, int n){
  int i = blockIdx.x * blockDim.x + threadIdx.x;
  if (i < n) o[i] = a[i] + b[i];
}

// ---------------- transpose: WT[c*R+r] = W[r*C+c], W is RxC ----------------
__global__ void transpose_kernel(const float* __restrict__ W, float* __restrict__ WT, int R, int C){
  int i = blockIdx.x * blockDim.x + threadIdx.x;
  if (i < R * C){ int r = i / C, c = i % C; WT[(size_t)c * R + r] = W[i]; }
}

// ---------------- fp32 -> bf16 with column zero-padding ----------------
__global__ void f2bf_pad_kernel(const float* __restrict__ in, bf16_t* __restrict__ out,
                                int R, int Kin, int Kout){
  int idx = blockIdx.x * blockDim.x + threadIdx.x;
  int total = R * Kout;
  if (idx >= total) return;
  int r = idx / Kout, k = idx % Kout;
  out[idx] = (k < Kin) ? f2bf(in[(size_t)r * Kin + k]) : (bf16_t)0;
}

// ---------------- data batchnorm: x(N,C,T,V,M) -> h1[(nm*C+c)*T+t][V] ----------------
__global__ void data_bn_kernel(const float* __restrict__ x, const float* __restrict__ g,
                               const float* __restrict__ bb, float* __restrict__ h1,
                               int N, int C, int T, int V, int M){
  int ch = blockIdx.x;             // (m*V + v)*C + c
  int m = ch / (V * C);
  int v = (ch / C) % V;
  int c = ch % C;
  int tid = threadIdx.x;
  int cnt = N * T;
  float s = 0.f, s2 = 0.f;
  for (int i = tid; i < cnt; i += 64){
    int n = i / T, t = i % T;
    float val = x[(((size_t)(n * C + c) * T + t) * V + v) * M + m];
    s += val; s2 += val * val;
  }
  for (int off = 32; off; off >>= 1){ s += __shfl_down(s, off); s2 += __shfl_down(s2, off); }
  s = __shfl(s, 0); s2 = __shfl(s2, 0);
  float mean = s / cnt;
  float rstd = rsqrtf(s2 / cnt - mean * mean + 1e-5f);
  float gg = g[ch], bo = bb[ch];
  for (int i = tid; i < cnt; i += 64){
    int n = i / T, t = i % T;
    float val = x[(((size_t)(n * C + c) * T + t) * V + v) * M + m];
    float y = (val - mean) * rstd * gg + bo;
    h1[((size_t)((n * M + m) * C + c) * T + t) * V + v] = y;
  }
}

// ---------------- support: sup[row][w] = sum_u A[w][u]*hin[row][u] ----------------
__global__ void support1_kernel(const float* __restrict__ A, const float* __restrict__ hin,
                                float* __restrict__ sup, int total){
  int idx = blockIdx.x * blockDim.x + threadIdx.x;
  if (idx >= total) return;
  int w = idx % 325;
  int rest = idx / 325;
  const float* row = hin + (size_t)rest * 25;
  const float* ar = A + w * 25;
  float acc = 0.f;
  #pragma unroll
  for (int u = 0; u < 25; ++u) acc += ar[u] * row[u];
  sup[idx] = acc;
}

// ---------------- gcn1 output: y1[((nm*T+t)*25+v)*96+o] ----------------
__global__ void gcn1_out_kernel(const float* __restrict__ sup, const float* __restrict__ W1,
                                const float* __restrict__ b1, float* __restrict__ y1, int NM, int T){
  int idx = blockIdx.x * blockDim.x + threadIdx.x;
  int total = NM * T * 25 * 96;
  if (idx >= total) return;
  int o = idx % 96;
  int v = (idx / 96) % 25;
  int t = (idx / (96 * 25)) % T;
  int nm = idx / (96 * 25 * T);
  float acc = b1[o];
  #pragma unroll
  for (int k = 0; k < 13; ++k)
    #pragma unroll
    for (int c = 0; c < 3; ++c)
      acc += W1[o * 39 + k * 3 + c] * sup[(size_t)((nm * 3 + c) * T + t) * 325 + k * 25 + v];
  y1[idx] = acc;
}

// ---------------- per-column stats of mat[R][Cc] ----------------
__global__ void colstats_kernel(const float* __restrict__ mat, int R, int Cc,
                                float* __restrict__ mean, float* __restrict__ rstd){
  int col = blockIdx.x;
  float s = 0.f, s2 = 0.f;
  for (int r = threadIdx.x; r < R; r += blockDim.x){
    float v = mat[(size_t)r * Cc + col]; s += v; s2 += v * v;
  }
  __shared__ float sa[4], sb[4];
  int lane = threadIdx.x & 63, wid = threadIdx.x >> 6;
  for (int off = 32; off; off >>= 1){ s += __shfl_down(s, off); s2 += __shfl_down(s2, off); }
  if (lane == 0){ sa[wid] = s; sb[wid] = s2; }
  __syncthreads();
  if (threadIdx.x == 0){
    s = sa[0] + sa[1] + sa[2] + sa[3];
    s2 = sb[0] + sb[1] + sb[2] + sb[3];
    float m = s / R;
    mean[col] = m;
    rstd[col] = rsqrtf(s2 / R - m * m + 1e-5f);
  }
}

// ---------------- bn + relu + transpose to sequence layout ----------------
__global__ void bn_relu_seq_kernel(const float* __restrict__ ymat, const float* __restrict__ mean,
                                   const float* __restrict__ rstd, const float* __restrict__ g,
                                   const float* __restrict__ bb, float* __restrict__ xseq,
                                   int NM, int T, int H){
  int idx = blockIdx.x * blockDim.x + threadIdx.x;
  int total = NM * T * 25 * H;
  if (idx >= total) return;
  int o = idx % H;
  int v = (idx / H) % 25;
  int t = (idx / (H * 25)) % T;
  int nm = idx / (H * 25 * T);
  float val = (ymat[idx] - mean[o]) * rstd[o] * g[o] + bb[o];
  val = fmaxf(val, 0.f);
  int b = nm * 25 + v;
  xseq[((size_t)b * T + t) * H + o] = val;
}

// ---------------- log-signature features -> bf16 rows (K-padded) ----------------
struct SegTable { int st[50]; int en[50]; };

__global__ void feats_kernel(const float* __restrict__ xseq, bf16_t* __restrict__ feats,
                             SegTable segs, int T, int d, int S, int L, int pairs, int rowlenP){
  __shared__ float pts[4][192];
  int bs = blockIdx.x;
  int b = bs / S, s = bs % S;
  int st = segs.st[s], en = segs.en[s];
  int nt = blockDim.x, tid = threadIdx.x;
  for (int l = 0; l < L; ++l){
    int t = st + l; if (t > en) t = en;
    for (int i = tid; i < d; i += nt) pts[l][i] = xseq[((size_t)b * T + t) * d + i];
  }
  __syncthreads();
  int rowlen = 2 * d + pairs;
  bf16_t* frow = feats + (size_t)bs * rowlenP;
  for (int i = tid; i < d; i += nt){
    frow[i] = f2bf(pts[0][i]);
    frow[d + i] = f2bf(pts[L - 1][i] - pts[0][i]);
  }
  for (int i = tid + rowlen; i < rowlenP; i += nt) frow[i] = 0;  // K pad
  for (int i = 0; i < d - 1; ++i){
    int base = 2 * d + i * (d - 1) - (i * (i - 1)) / 2;
    float reli[3], dxi[3];
    #pragma unroll
    for (int l = 1; l <= 2; ++l){
      if (l <= L - 2){
        reli[l] = pts[l][i] - pts[0][i];
        dxi[l]  = pts[l + 1][i] - pts[l][i];
      } else { reli[l] = 0.f; dxi[l] = 0.f; }
    }
    int rl = d - 1 - i;
    for (int jj = tid; jj < rl; jj += nt){
      int j = i + 1 + jj;
      float acc = 0.f;
      for (int l = 1; l <= L - 2; ++l){
        float relj = pts[l][j] - pts[0][j];
        float dxj  = pts[l + 1][j] - pts[l][j];
        acc += reli[l] * dxj - relj * dxi[l];
      }
      frow[base + jj] = f2bf(0.5f * acc);
    }
  }
}

// ---------------- MFMA bf16 NT GEMM: C[M][N] = A[M][K] * B[N][K]^T + bias ----------------
// 128x128 tile, BK=32, 4 waves of 64x64, global_load_lds staging.
// Requires: K % 32 == 0, N % 128 == 0. M edge handled by clamp+predicate.
__global__ __launch_bounds__(256)
void gemm_mfma_nt(const bf16_t* __restrict__ A, const bf16_t* __restrict__ B,
                  const float* __restrict__ bias, float* __restrict__ C,
                  int M, int N, int K){
  __shared__ bf16_t As[128 * 32];
  __shared__ bf16_t Bs[128 * 32];
  const int tid = threadIdx.x;
  const int lane = tid & 63, wv = tid >> 6;
  const int bm = blockIdx.x * 128, bn = blockIdx.y * 128;
  const int wr = (wv >> 1) * 64, wc = (wv & 1) * 64;
  const int m_l = lane & 15, q = lane >> 4;

  // staging source pointers (2 chunks each for A and B)
  const bf16_t* gA[2]; const bf16_t* gB[2];
  bf16_t* lA[2]; bf16_t* lB[2];
  #pragma unroll
  for (int it = 0; it < 2; ++it){
    int c = it * 4 + wv;
    int rowA = bm + c * 16 + (lane >> 2);
    if (rowA > M - 1) rowA = M - 1;           // clamp (stores predicated)
    int rowB = bn + c * 16 + (lane >> 2);     // N divisible by 128
    int col = (lane & 3) * 8;
    gA[it] = A + (size_t)rowA * K + col;
    gB[it] = B + (size_t)rowB * K + col;
    lA[it] = &As[c * 512];
    lB[it] = &Bs[c * 512];
  }
  // fragment read pointers
  const bf16_t* pa[4]; const bf16_t* pb[4];
  #pragma unroll
  for (int i = 0; i < 4; ++i){
    pa[i] = &As[(wr + i * 16 + m_l) * 32 + q * 8];
    pb[i] = &Bs[(wc + i * 16 + m_l) * 32 + q * 8];
  }

  floatx4 acc[4][4] = {};
  for (int k0 = 0; k0 < K; k0 += 32){
    __syncthreads();
    gload_lds16(gA[0] + k0, lA[0]);
    gload_lds16(gA[1] + k0, lA[1]);
    gload_lds16(gB[0] + k0, lB[0]);
    gload_lds16(gB[1] + k0, lB[1]);
    __syncthreads();
    short8 af[4], bfr[4];
    #pragma unroll
    for (int i = 0; i < 4; ++i){
      af[i]  = *reinterpret_cast<const short8*>(pa[i]);
      bfr[i] = *reinterpret_cast<const short8*>(pb[i]);
    }
    #pragma unroll
    for (int mi = 0; mi < 4; ++mi)
      #pragma unroll
      for (int ni = 0; ni < 4; ++ni)
        acc[mi][ni] = __builtin_amdgcn_mfma_f32_16x16x32_bf16(af[mi], bfr[ni], acc[mi][ni], 0, 0, 0);
  }

  #pragma unroll
  for (int mi = 0; mi < 4; ++mi){
    int row0 = bm + wr + mi * 16 + q * 4;
    #pragma unroll
    for (int r = 0; r < 4; ++r){
      int row = row0 + r;
      if (row < M){
        #pragma unroll
        for (int ni = 0; ni < 4; ++ni){
          int col = bn + wc + ni * 16 + m_l;
          C[(size_t)row * N + col] = acc[mi][ni][r] + bias[col];
        }
      }
    }
  }
}

// ---------------- fp32 tiled GEMM (kept for GCN2): C = A[M][K]*B[N][K]^T + bias ----------------
template <typename TA>
__global__ __launch_bounds__(256)
void gemm_nt_kernel(const TA* __restrict__ A, const float* __restrict__ B,
                    const float* __restrict__ bias, float* __restrict__ C,
                    int M, int N, int K){
  __shared__ float As[32][68];
  __shared__ float Bs[32][68];
  const int tid = threadIdx.x;
  const int tx = tid & 15, ty = tid >> 4;
  const int bm = blockIdx.x * 64, bn = blockIdx.y * 64;
  const int lr = tid >> 2;
  const int lc = (tid & 3) * 8;
  float acc[4][4] = {};
  for (int k0 = 0; k0 < K; k0 += 32){
    {
      int row = bm + lr;
      float va[8];
      if (row < M && (k0 + lc + 8) <= K){
        const float4* p = reinterpret_cast<const float4*>(A + (size_t)row * K + k0 + lc);
        float4 x0 = p[0], x1 = p[1];
        va[0] = x0.x; va[1] = x0.y; va[2] = x0.z; va[3] = x0.w;
        va[4] = x1.x; va[5] = x1.y; va[6] = x1.z; va[7] = x1.w;
      } else {
        #pragma unroll
        for (int j = 0; j < 8; ++j){
          int k = k0 + lc + j;
          va[j] = (row < M && k < K) ? (float)A[(size_t)row * K + k] : 0.f;
        }
      }
      #pragma unroll
      for (int j = 0; j < 8; ++j) As[lc + j][lr] = va[j];
    }
    {
      int row = bn + lr;
      float vb[8];
      if (row < N && (k0 + lc + 8) <= K){
        const float4* p = reinterpret_cast<const float4*>(B + (size_t)row * K + k0 + lc);
        float4 x0 = p[0], x1 = p[1];
        vb[0] = x0.x; vb[1] = x0.y; vb[2] = x0.z; vb[3] = x0.w;
        vb[4] = x1.x; vb[5] = x1.y; vb[6] = x1.z; vb[7] = x1.w;
      } else {
        #pragma unroll
        for (int j = 0; j < 8; ++j){
          int k = k0 + lc + j;
          vb[j] = (row < N && k < K) ? B[(size_t)row * K + k] : 0.f;
        }
      }
      #pragma unroll
      for (int j = 0; j < 8; ++j) Bs[lc + j][lr] = vb[j];
    }
    __syncthreads();
    #pragma unroll
    for (int kk = 0; kk < 32; ++kk){
      const float4 a = *reinterpret_cast<const float4*>(&As[kk][ty * 4]);
      const float4 b = *reinterpret_cast<const float4*>(&Bs[kk][tx * 4]);
      acc[0][0] += a.x * b.x; acc[0][1] += a.x * b.y; acc[0][2] += a.x * b.z; acc[0][3] += a.x * b.w;
      acc[1][0] += a.y * b.x; acc[1][1] += a.y * b.y; acc[1][2] += a.y * b.z; acc[1][3] += a.y * b.w;
      acc[2][0] += a.z * b.x; acc[2][1] += a.z * b.y; acc[2][2] += a.z * b.z; acc[2][3] += a.z * b.w;
      acc[3][0] += a.w * b.x; acc[3][1] += a.w * b.y; acc[3][2] += a.w * b.z; acc[3][3] += a.w * b.w;
    }
    __syncthreads();
  }
  #pragma unroll
  for (int i = 0; i < 4; ++i){
    int row = bm + ty * 4 + i;
    if (row >= M) continue;
    #pragma unroll
    for (int j = 0; j < 4; ++j){
      int col = bn + tx * 4 + j;
      if (col >= N) continue;
      float r = acc[i][j];
      if (bias) r += bias[col];
      C[(size_t)row * N + col] = r;
    }
  }
}

// ---------------- persistent per-sequence LSTM ----------------
__global__ void lstm_kernel(const float* __restrict__ xp, const float* __restrict__ WhhT,
                            float* __restrict__ out, int S, int H){
  extern __shared__ float sm[];
  float* hv = sm;
  float* cv = sm + H;
  float* gv = sm + 2 * H;
  int b = blockIdx.x;
  int t = threadIdx.x;
  int H4 = 4 * H;
  if (t < H){ hv[t] = 0.f; cv[t] = 0.f; }
  __syncthreads();
  for (int s = 0; s < S; ++s){
    float acc = xp[((size_t)b * S + s) * H4 + t];
    for (int j = 0; j < H; j += 4){
      acc += WhhT[(size_t)j * H4 + t]       * hv[j]
           + WhhT[(size_t)(j + 1) * H4 + t] * hv[j + 1]
           + WhhT[(size_t)(j + 2) * H4 + t] * hv[j + 2]
           + WhhT[(size_t)(j + 3) * H4 + t] * hv[j + 3];
    }
    gv[t] = acc;
    __syncthreads();
    if (t < H){
      float ig = sigf(gv[t]);
      float fg = sigf(gv[H + t]);
      float gg = tanhf(gv[2 * H + t]);
      float og = sigf(gv[3 * H + t]);
      float cc = fg * cv[t] + ig * gg;
      cv[t] = cc;
      float hh = og * tanhf(cc);
      hv[t] = hh;
      out[((size_t)b * S + s) * H + t] = hh;
    }
    __syncthreads();
  }
}

// ---------------- per-segment stats over (b,h) ----------------
__global__ void segstats_kernel(const float* __restrict__ lout, int B, int S, int H,
                                float* __restrict__ mean, float* __restrict__ rstd){
  int s = blockIdx.x;
  float sum = 0.f, sum2 = 0.f;
  int cnt = B * H;
  for (int i = threadIdx.x; i < cnt; i += blockDim.x){
    int b = i / H, hh = i % H;
    float v = lout[((size_t)b * S + s) * H + hh];
    sum += v; sum2 += v * v;
  }
  __shared__ float sa[4], sb[4];
  int lane = threadIdx.x & 63, wid = threadIdx.x >> 6;
  for (int off = 32; off; off >>= 1){ sum += __shfl_down(sum, off); sum2 += __shfl_down(sum2, off); }
  if (lane == 0){ sa[wid] = sum; sb[wid] = sum2; }
  __syncthreads();
  if (threadIdx.x == 0){
    sum = sa[0] + sa[1] + sa[2] + sa[3];
    sum2 = sb[0] + sb[1] + sb[2] + sb[3];
    float m = sum / cnt;
    mean[s] = m;
    rstd[s] = rsqrtf(sum2 / cnt - m * m + 1e-5f);
  }
}

// ---------------- bnseg apply + transpose to gcn2 input layout ----------------
__global__ void bnseg_to_g2in_kernel(const float* __restrict__ lout, const float* __restrict__ mean,
                                     const float* __restrict__ rstd, const float* __restrict__ g,
                                     const float* __restrict__ bb, float* __restrict__ g2in,
                                     int B, int S, int H){
  int idx = blockIdx.x * blockDim.x + threadIdx.x;
  int total = B * S * H;
  if (idx >= total) return;
  int hh = idx % H;
  int s = (idx / H) % S;
  int b = idx / (H * S);
  float val = (lout[idx] - mean[s]) * rstd[s] * g[s] + bb[s];
  int nm = b / 25, v = b % 25;
  g2in[((size_t)((nm * H + hh) * S) + s) * 25 + v] = val;
}

// ---------------- support2 -> A2mat[(nm*S+s)*25+v][k*96+c] ----------------
__global__ void support2_kernel(const float* __restrict__ A, const float* __restrict__ g2in,
                                float* __restrict__ A2mat, int NM, int C1, int S){
  int idx = blockIdx.x * blockDim.x + threadIdx.x;
  int total = NM * C1 * S * 325;
  if (idx >= total) return;
  int w = idx % 325;
  int s = (idx / 325) % S;
  int c = (idx / (325 * S)) % C1;
  int nm = idx / (325 * S * C1);
  const float* row = g2in + ((size_t)((nm * C1 + c) * S) + s) * 25;
  const float* ar = A + w * 25;
  float acc = 0.f;
  #pragma unroll
  for (int u = 0; u < 25; ++u) acc += ar[u] * row[u];
  int k = w / 25, v = w % 25;
  A2mat[((size_t)((nm * S + s) * 25 + v)) * 1248 + k * C1 + c] = acc;
}

// ---------------- bnseg2 + global pool ----------------
__global__ void pool_kernel(const float* __restrict__ lout2, const float* __restrict__ mean,
                            const float* __restrict__ rstd, const float* __restrict__ g,
                            const float* __restrict__ bb, float* __restrict__ pooled,
                            int S, int H){
  int n = blockIdx.x / H;
  int o = blockIdx.x % H;
  float sum = 0.f;
  int cnt = 2 * 25 * S;
  for (int i = threadIdx.x; i < cnt; i += 64){
    int m = i / (25 * S);
    int r = i % (25 * S);
    int v = r / S;
    int s = r % S;
    int b = (n * 2 + m) * 25 + v;
    float val = lout2[((size_t)b * S + s) * H + o];
    val = (val - mean[s]) * rstd[s] * g[s] + bb[s];
    sum += val;
  }
  for (int off = 32; off; off >>= 1) sum += __shfl_down(sum, off);
  if (threadIdx.x == 0) pooled[n * H + o] = sum / cnt;
}

// ---------------- final FC ----------------
__global__ void fc_kernel(const float* __restrict__ pooled, const float* __restrict__ fcW,
                          const float* __restrict__ fcb, float* __restrict__ outp){
  int idx = blockIdx.x * blockDim.x + threadIdx.x;
  if (idx >= 120) return;
  int n = idx / 60, cls = idx % 60;
  float acc = fcb[cls];
  for (int o = 0; o < 192; ++o) acc += pooled[n * 192 + o] * fcW[cls * 192 + o];
  outp[idx] = acc;
}

// ---------------- host: replicate np.linspace + python round (ties-to-even) ----------------
static void make_segs(int T, int S, SegTable& tab, int& L){
  double step = (double)(T - 1) / (double)S;
  long long tv[51];
  for (int i = 0; i <= S; ++i){
    double v = 1.0 + step * (double)i;
    tv[i] = llrint(v);
  }
  L = 0;
  for (int s = 0; s < S; ++s){
    tab.st[s] = (int)tv[s] - 1;
    tab.en[s] = (int)tv[s + 1] - 1;
    int len = tab.en[s] - tab.st[s] + 1;
    if (len > L) L = len;
  }
  for (int s = S; s < 50; ++s){ tab.st[s] = 0; tab.en[s] = 0; }
  if (L > 4) L = 4;
}

extern "C" void kernel_launch(void* const* d_in, const int* in_sizes, int n_in,
                              void* d_out, int out_size, void* d_ws, size_t ws_size,
                              hipStream_t stream){
  const float* x         = (const float*)d_in[0];
  const float* data_bn_g = (const float*)d_in[2];
  const float* data_bn_b = (const float*)d_in[3];
  const float* A_powers1 = (const float*)d_in[4];
  const float* A_res1    = (const float*)d_in[5];
  const float* W1        = (const float*)d_in[6];
  const float* b1        = (const float*)d_in[7];
  const float* bn1_g     = (const float*)d_in[8];
  const float* bn1_b     = (const float*)d_in[9];
  const float* Wih1      = (const float*)d_in[10];
  const float* Whh1      = (const float*)d_in[11];
  const float* bih1      = (const float*)d_in[12];
  const float* bhh1      = (const float*)d_in[13];
  const float* bnseg1_g  = (const float*)d_in[14];
  const float* bnseg1_b  = (const float*)d_in[15];
  const float* A_powers2 = (const float*)d_in[16];
  const float* A_res2    = (const float*)d_in[17];
  const float* W2        = (const float*)d_in[18];
  const float* b2        = (const float*)d_in[19];
  const float* bn2_g     = (const float*)d_in[20];
  const float* bn2_b     = (const float*)d_in[21];
  const float* Wih2      = (const float*)d_in[22];
  const float* Whh2      = (const float*)d_in[23];
  const float* bih2      = (const float*)d_in[24];
  const float* bhh2      = (const float*)d_in[25];
  const float* bnseg2_g  = (const float*)d_in[26];
  const float* bnseg2_b  = (const float*)d_in[27];
  const float* fcW       = (const float*)d_in[28];
  const float* fcb       = (const float*)d_in[29];
  float* out = (float*)d_out;

  const int N = 2, C = 3, T = 100, V = 25, M = 2, NM = 4;
  const int K = 13, C1 = 96, C2 = 192;
  const int S1 = 50, S2 = 30;
  const int B = 100;
  const int IN1 = 4752, IN2 = 18720;
  const int IN1P = 4768;               // K padded to %32
  const int P1 = 4560, P2 = 18336;

  size_t off = 0;
  char* base = (char*)d_ws;
  auto alloc = [&](size_t nbytes) -> void* {
    off = (off + 255) & ~(size_t)255;
    void* p = base + off;
    off += nbytes;
    return p;
  };
  float* A1full = (float*)alloc(325 * 25 * 4);
  float* A2full = (float*)alloc(325 * 25 * 4);
  float* h1     = (float*)alloc((size_t)NM * C * T * V * 4);
  float* sup1   = (float*)alloc((size_t)NM * C * T * 325 * 4);
  float* y1mat  = (float*)alloc((size_t)NM * T * V * C1 * 4);
  float* meanb  = (float*)alloc(1024);
  float* rstdb  = (float*)alloc(1024);
  float* xseq1  = (float*)alloc((size_t)B * T * C1 * 4);
  float* xp1    = (float*)alloc((size_t)B * S1 * 4 * C1 * 4);
  float* l1out  = (float*)alloc((size_t)B * S1 * C1 * 4);
  float* g2in   = (float*)alloc((size_t)NM * C1 * S1 * V * 4);
  float* A2mat  = (float*)alloc((size_t)NM * S1 * V * (K * C1) * 4);
  float* y2mat  = (float*)alloc((size_t)NM * S1 * V * C2 * 4);
  float* xseq2  = (float*)alloc((size_t)B * S1 * C2 * 4);
  float* xp2    = (float*)alloc((size_t)B * S2 * 4 * C2 * 4);
  float* l2out  = (float*)alloc((size_t)B * S2 * C2 * 4);
  float* pooled = (float*)alloc(2 * C2 * 4);
  float* bias1  = (float*)alloc(4 * C1 * 4);
  float* bias2  = (float*)alloc(4 * C2 * 4);
  float* WhhT1  = (float*)alloc((size_t)4 * C1 * C1 * 4);
  float* WhhT2  = (float*)alloc((size_t)4 * C2 * C2 * 4);
  bf16_t* Wih1b = (bf16_t*)alloc((size_t)4 * C1 * IN1P * 2);
  bf16_t* Wih2b = (bf16_t*)alloc((size_t)4 * C2 * IN2 * 2);
  // shared big buffer: feats1 (5000 x 4768) then feats2 (3000 x 18720), bf16
  bf16_t* feats = (bf16_t*)alloc((size_t)B * S2 * IN2 * 2);
  (void)ws_size; (void)in_sizes; (void)n_in; (void)out_size;

  // constant prep
  vadd_kernel<<<(8125 + 255) / 256, 256, 0, stream>>>(A_powers1, A_res1, A1full, 8125);
  vadd_kernel<<<(8125 + 255) / 256, 256, 0, stream>>>(A_powers2, A_res2, A2full, 8125);
  vadd_kernel<<<2, 256, 0, stream>>>(bih1, bhh1, bias1, 4 * C1);
  vadd_kernel<<<3, 256, 0, stream>>>(bih2, bhh2, bias2, 4 * C2);
  transpose_kernel<<<(4 * C1 * C1 + 255) / 256, 256, 0, stream>>>(Whh1, WhhT1, 4 * C1, C1);
  transpose_kernel<<<(4 * C2 * C2 + 255) / 256, 256, 0, stream>>>(Whh2, WhhT2, 4 * C2, C2);
  f2bf_pad_kernel<<<(4 * C1 * IN1P + 255) / 256, 256, 0, stream>>>(Wih1, Wih1b, 4 * C1, IN1, IN1P);
  f2bf_pad_kernel<<<(4 * C2 * IN2 + 255) / 256, 256, 0, stream>>>(Wih2, Wih2b, 4 * C2, IN2, IN2);

  // stage 0: data BN
  data_bn_kernel<<<M * V * C, 64, 0, stream>>>(x, data_bn_g, data_bn_b, h1, N, C, T, V, M);

  // stage 1: GCN1
  int tot_sup1 = NM * C * T * 325;
  support1_kernel<<<(tot_sup1 + 255) / 256, 256, 0, stream>>>(A1full, h1, sup1, tot_sup1);
  int tot_y1 = NM * T * 25 * C1;
  gcn1_out_kernel<<<(tot_y1 + 255) / 256, 256, 0, stream>>>(sup1, W1, b1, y1mat, NM, T);
  colstats_kernel<<<C1, 256, 0, stream>>>(y1mat, NM * T * 25, C1, meanb, rstdb);
  bn_relu_seq_kernel<<<(tot_y1 + 255) / 256, 256, 0, stream>>>(y1mat, meanb, rstdb, bn1_g, bn1_b,
                                                               xseq1, NM, T, C1);

  // stage 1: logsig-rnn
  SegTable seg1, seg2; int L1, L2;
  make_segs(T, S1, seg1, L1);
  make_segs(S1, S2, seg2, L2);

  feats_kernel<<<B * S1, 256, 0, stream>>>(xseq1, feats, seg1, T, C1, S1, L1, P1, IN1P);
  {
    dim3 g((B * S1 + 127) / 128, (4 * C1) / 128);
    gemm_mfma_nt<<<g, 256, 0, stream>>>(feats, Wih1b, bias1, xp1, B * S1, 4 * C1, IN1P);
  }
  lstm_kernel<<<B, 4 * C1, 6 * C1 * 4, stream>>>(xp1, WhhT1, l1out, S1, C1);
  segstats_kernel<<<S1, 256, 0, stream>>>(l1out, B, S1, C1, meanb, rstdb);
  int tot_bn1 = B * S1 * C1;
  bnseg_to_g2in_kernel<<<(tot_bn1 + 255) / 256, 256, 0, stream>>>(l1out, meanb, rstdb, bnseg1_g,
                                                                  bnseg1_b, g2in, B, S1, C1);

  // stage 2: GCN2
  int tot_sup2 = NM * C1 * S1 * 325;
  support2_kernel<<<(tot_sup2 + 255) / 256, 256, 0, stream>>>(A2full, g2in, A2mat, NM, C1, S1);
  {
    dim3 g((NM * S1 * 25 + 63) / 64, (C2 + 63) / 64);
    gemm_nt_kernel<float><<<g, 256, 0, stream>>>(A2mat, W2, b2, y2mat, NM * S1 * 25, C2, K * C1);
  }
  colstats_kernel<<<C2, 256, 0, stream>>>(y2mat, NM * S1 * 25, C2, meanb, rstdb);
  int tot_y2 = NM * S1 * 25 * C2;
  bn_relu_seq_kernel<<<(tot_y2 + 255) / 256, 256, 0, stream>>>(y2mat, meanb, rstdb, bn2_g, bn2_b,
                                                               xseq2, NM, S1, C2);

  // stage 2: logsig-rnn
  feats_kernel<<<B * S2, 256, 0, stream>>>(xseq2, feats, seg2, S1, C2, S2, L2, P2, IN2);
  {
    dim3 g((B * S2 + 127) / 128, (4 * C2) / 128);
    gemm_mfma_nt<<<g, 256, 0, stream>>>(feats, Wih2b, bias2, xp2, B * S2, 4 * C2, IN2);
  }
  lstm_kernel<<<B, 4 * C2, 6 * C2 * 4, stream>>>(xp2, WhhT2, l2out, S2, C2);
  segstats_kernel<<<S2, 256, 0, stream>>>(l2out, B, S2, C2, meanb, rstdb);

  // pool + fc
  pool_kernel<<<2 * C2, 64, 0, stream>>>(l2out, meanb, rstdb, bnseg2_g, bnseg2_b, pooled, S2, C2);
  fc_kernel<<<1, 128, 0, stream>>>(pooled, fcW, fcb, out);
}

// Round 3
// 1021.487 us; speedup vs baseline: 2.9250x; 1.5166x over previous
//
#include <hip/hip_runtime.h>
#include <cmath>
#include <cstdint>
#include <cstddef>

typedef unsigned short bf16_t;
typedef __attribute__((ext_vector_type(8))) short short8;
typedef __attribute__((ext_vector_type(4))) float floatx4;

__device__ __forceinline__ float bf2f(bf16_t b){
  unsigned int u = ((unsigned int)b) << 16;
  return __uint_as_float(u);
}
__device__ __forceinline__ float bf2f_u(unsigned int u16){
  return __uint_as_float(u16 << 16);
}
__device__ __forceinline__ bf16_t f2bf(float f){
  unsigned int u = __float_as_uint(f);
  unsigned int r = (u + 0x7fffu + ((u >> 16) & 1u)) >> 16;  // RNE
  return (bf16_t)r;
}
__device__ __forceinline__ float sigf(float x){ return 1.0f / (1.0f + expf(-x)); }

__device__ __forceinline__ void gload_lds16(const bf16_t* g, bf16_t* lds){
  __builtin_amdgcn_global_load_lds(
      (const __attribute__((address_space(1))) unsigned int*)g,
      (__attribute__((address_space(3))) unsigned int*)lds, 16, 0, 0);
}

// ---------------- elementwise add ----------------
__global__ void vadd_kernel(const float* __restrict__ a, const float* __restrict__ b,
                            float* __restrict__ o, int n){
  int i = blockIdx.x * blockDim.x + threadIdx.x;
  if (i < n) o[i] = a[i] + b[i];
}

// ---------------- fp32 -> bf16 with column zero-padding ----------------
__global__ void f2bf_pad_kernel(const float* __restrict__ in, bf16_t* __restrict__ out,
                                int R, int Kin, int Kout){
  int idx = blockIdx.x * blockDim.x + threadIdx.x;
  int total = R * Kout;
  if (idx >= total) return;
  int r = idx / Kout, k = idx % Kout;
  out[idx] = (k < Kin) ? f2bf(in[(size_t)r * Kin + k]) : (bf16_t)0;
}

// ---------------- pack Whh[t][j] (t over 4H, j over H) into bf16 pairs over j ----------------
// Wp[j2*H4 + t] = (bf16(Whh[t][2*j2]), bf16(Whh[t][2*j2+1]))
__global__ void pack_whh_kernel(const float* __restrict__ Whh, unsigned int* __restrict__ Wp, int H){
  int H4 = 4 * H, H2 = H / 2;
  int idx = blockIdx.x * blockDim.x + threadIdx.x;
  if (idx >= H4 * H2) return;
  int t = idx % H4, j2 = idx / H4;
  unsigned int lo = f2bf(Whh[(size_t)t * H + 2 * j2]);
  unsigned int hi = f2bf(Whh[(size_t)t * H + 2 * j2 + 1]);
  Wp[idx] = lo | (hi << 16);
}

// ---------------- data batchnorm: x(N,C,T,V,M) -> h1[(nm*C+c)*T+t][V] ----------------
__global__ void data_bn_kernel(const float* __restrict__ x, const float* __restrict__ g,
                               const float* __restrict__ bb, float* __restrict__ h1,
                               int N, int C, int T, int V, int M){
  int ch = blockIdx.x;             // (m*V + v)*C + c
  int m = ch / (V * C);
  int v = (ch / C) % V;
  int c = ch % C;
  int tid = threadIdx.x;
  int cnt = N * T;
  float s = 0.f, s2 = 0.f;
  for (int i = tid; i < cnt; i += 64){
    int n = i / T, t = i % T;
    float val = x[(((size_t)(n * C + c) * T + t) * V + v) * M + m];
    s += val; s2 += val * val;
  }
  for (int off = 32; off; off >>= 1){ s += __shfl_down(s, off); s2 += __shfl_down(s2, off); }
  s = __shfl(s, 0); s2 = __shfl(s2, 0);
  float mean = s / cnt;
  float rstd = rsqrtf(s2 / cnt - mean * mean + 1e-5f);
  float gg = g[ch], bo = bb[ch];
  for (int i = tid; i < cnt; i += 64){
    int n = i / T, t = i % T;
    float val = x[(((size_t)(n * C + c) * T + t) * V + v) * M + m];
    float y = (val - mean) * rstd * gg + bo;
    h1[((size_t)((n * M + m) * C + c) * T + t) * V + v] = y;
  }
}

// ---------------- support1: sup[row][w] = sum_u A[w][u]*hin[row][u] ----------------
__global__ void support1_kernel(const float* __restrict__ A, const float* __restrict__ hin,
                                float* __restrict__ sup, int total){
  int idx = blockIdx.x * blockDim.x + threadIdx.x;
  if (idx >= total) return;
  int w = idx % 325;
  int rest = idx / 325;
  const float* row = hin + (size_t)rest * 25;
  const float* ar = A + w * 25;
  float acc = 0.f;
  #pragma unroll
  for (int u = 0; u < 25; ++u) acc += ar[u] * row[u];
  sup[idx] = acc;
}

// ---------------- gcn1 output: y1[((nm*T+t)*25+v)*96+o] ----------------
__global__ void gcn1_out_kernel(const float* __restrict__ sup, const float* __restrict__ W1,
                                const float* __restrict__ b1, float* __restrict__ y1, int NM, int T){
  int idx = blockIdx.x * blockDim.x + threadIdx.x;
  int total = NM * T * 25 * 96;
  if (idx >= total) return;
  int o = idx % 96;
  int v = (idx / 96) % 25;
  int t = (idx / (96 * 25)) % T;
  int nm = idx / (96 * 25 * T);
  float acc = b1[o];
  #pragma unroll
  for (int k = 0; k < 13; ++k)
    #pragma unroll
    for (int c = 0; c < 3; ++c)
      acc += W1[o * 39 + k * 3 + c] * sup[(size_t)((nm * 3 + c) * T + t) * 325 + k * 25 + v];
  y1[idx] = acc;
}

// ---------------- per-column stats of mat[R][Cc] ----------------
__global__ void colstats_kernel(const float* __restrict__ mat, int R, int Cc,
                                float* __restrict__ mean, float* __restrict__ rstd){
  int col = blockIdx.x;
  float s = 0.f, s2 = 0.f;
  for (int r = threadIdx.x; r < R; r += blockDim.x){
    float v = mat[(size_t)r * Cc + col]; s += v; s2 += v * v;
  }
  __shared__ float sa[4], sb[4];
  int lane = threadIdx.x & 63, wid = threadIdx.x >> 6;
  for (int off = 32; off; off >>= 1){ s += __shfl_down(s, off); s2 += __shfl_down(s2, off); }
  if (lane == 0){ sa[wid] = s; sb[wid] = s2; }
  __syncthreads();
  if (threadIdx.x == 0){
    s = sa[0] + sa[1] + sa[2] + sa[3];
    s2 = sb[0] + sb[1] + sb[2] + sb[3];
    float m = s / R;
    mean[col] = m;
    rstd[col] = rsqrtf(s2 / R - m * m + 1e-5f);
  }
}

// ---------------- bn + relu + transpose to sequence layout ----------------
__global__ void bn_relu_seq_kernel(const float* __restrict__ ymat, const float* __restrict__ mean,
                                   const float* __restrict__ rstd, const float* __restrict__ g,
                                   const float* __restrict__ bb, float* __restrict__ xseq,
                                   int NM, int T, int H){
  int idx = blockIdx.x * blockDim.x + threadIdx.x;
  int total = NM * T * 25 * H;
  if (idx >= total) return;
  int o = idx % H;
  int v = (idx / H) % 25;
  int t = (idx / (H * 25)) % T;
  int nm = idx / (H * 25 * T);
  float val = (ymat[idx] - mean[o]) * rstd[o] * g[o] + bb[o];
  val = fmaxf(val, 0.f);
  int b = nm * 25 + v;
  xseq[((size_t)b * T + t) * H + o] = val;
}

// ---------------- log-signature features -> bf16 rows (K-padded) ----------------
struct SegTable { int st[50]; int en[50]; };

__global__ void feats_kernel(const float* __restrict__ xseq, bf16_t* __restrict__ feats,
                             SegTable segs, int T, int d, int S, int L, int pairs, int rowlenP){
  __shared__ float pts[4][192];
  int bs = blockIdx.x;
  int b = bs / S, s = bs % S;
  int st = segs.st[s], en = segs.en[s];
  int nt = blockDim.x, tid = threadIdx.x;
  for (int l = 0; l < L; ++l){
    int t = st + l; if (t > en) t = en;
    for (int i = tid; i < d; i += nt) pts[l][i] = xseq[((size_t)b * T + t) * d + i];
  }
  __syncthreads();
  int rowlen = 2 * d + pairs;
  bf16_t* frow = feats + (size_t)bs * rowlenP;
  for (int i = tid; i < d; i += nt){
    frow[i] = f2bf(pts[0][i]);
    frow[d + i] = f2bf(pts[L - 1][i] - pts[0][i]);
  }
  for (int i = tid + rowlen; i < rowlenP; i += nt) frow[i] = 0;  // K pad
  for (int i = 0; i < d - 1; ++i){
    int base = 2 * d + i * (d - 1) - (i * (i - 1)) / 2;
    float reli[3], dxi[3];
    #pragma unroll
    for (int l = 1; l <= 2; ++l){
      if (l <= L - 2){
        reli[l] = pts[l][i] - pts[0][i];
        dxi[l]  = pts[l + 1][i] - pts[l][i];
      } else { reli[l] = 0.f; dxi[l] = 0.f; }
    }
    int rl = d - 1 - i;
    for (int jj = tid; jj < rl; jj += nt){
      int j = i + 1 + jj;
      float acc = 0.f;
      for (int l = 1; l <= L - 2; ++l){
        float relj = pts[l][j] - pts[0][j];
        float dxj  = pts[l + 1][j] - pts[l][j];
        acc += reli[l] * dxj - relj * dxi[l];
      }
      frow[base + jj] = f2bf(0.5f * acc);
    }
  }
}

// ---------------- split-K MFMA bf16 NT GEMM: P[z] = A[M][K_z] * B[N][K_z]^T ----------------
// 128x128 tile, BK=32, 4 waves of 64x64, global_load_lds staging.
// Requires: K % 32 == 0. M/N edges handled by clamp+predicate.
__global__ __launch_bounds__(256)
void gemm_mfma_nt_split(const bf16_t* __restrict__ A, const bf16_t* __restrict__ B,
                        float* __restrict__ P, int M, int N, int K){
  __shared__ bf16_t As[128 * 32];
  __shared__ bf16_t Bs[128 * 32];
  const int tid = threadIdx.x;
  const int lane = tid & 63, wv = tid >> 6;
  const int bm = blockIdx.x * 128, bn = blockIdx.y * 128;
  const int wr = (wv >> 1) * 64, wc = (wv & 1) * 64;
  const int m_l = lane & 15, q = lane >> 4;

  const int ksteps = K >> 5;
  const int Z = gridDim.z, z = blockIdx.z;
  const int per = (ksteps + Z - 1) / Z;
  const int ks0 = z * per;
  const int ks1 = (ks0 + per < ksteps) ? ks0 + per : ksteps;

  const bf16_t* gA[2]; const bf16_t* gB[2];
  bf16_t* lA[2]; bf16_t* lB[2];
  #pragma unroll
  for (int it = 0; it < 2; ++it){
    int c = it * 4 + wv;
    int rowA = bm + c * 16 + (lane >> 2);
    if (rowA > M - 1) rowA = M - 1;
    int rowB = bn + c * 16 + (lane >> 2);
    if (rowB > N - 1) rowB = N - 1;
    int col = (lane & 3) * 8;
    gA[it] = A + (size_t)rowA * K + col;
    gB[it] = B + (size_t)rowB * K + col;
    lA[it] = &As[c * 512];
    lB[it] = &Bs[c * 512];
  }
  const bf16_t* pa[4]; const bf16_t* pb[4];
  #pragma unroll
  for (int i = 0; i < 4; ++i){
    pa[i] = &As[(wr + i * 16 + m_l) * 32 + q * 8];
    pb[i] = &Bs[(wc + i * 16 + m_l) * 32 + q * 8];
  }

  floatx4 acc[4][4] = {};
  for (int ks = ks0; ks < ks1; ++ks){
    int k0 = ks << 5;
    __syncthreads();
    gload_lds16(gA[0] + k0, lA[0]);
    gload_lds16(gA[1] + k0, lA[1]);
    gload_lds16(gB[0] + k0, lB[0]);
    gload_lds16(gB[1] + k0, lB[1]);
    __syncthreads();
    short8 af[4], bfr[4];
    #pragma unroll
    for (int i = 0; i < 4; ++i){
      af[i]  = *reinterpret_cast<const short8*>(pa[i]);
      bfr[i] = *reinterpret_cast<const short8*>(pb[i]);
    }
    #pragma unroll
    for (int mi = 0; mi < 4; ++mi)
      #pragma unroll
      for (int ni = 0; ni < 4; ++ni)
        acc[mi][ni] = __builtin_amdgcn_mfma_f32_16x16x32_bf16(af[mi], bfr[ni], acc[mi][ni], 0, 0, 0);
  }

  float* Pz = P + (size_t)z * M * N;
  #pragma unroll
  for (int mi = 0; mi < 4; ++mi){
    int row0 = bm + wr + mi * 16 + q * 4;
    #pragma unroll
    for (int r = 0; r < 4; ++r){
      int row = row0 + r;
      if (row < M){
        #pragma unroll
        for (int ni = 0; ni < 4; ++ni){
          int col = bn + wc + ni * 16 + m_l;
          if (col < N) Pz[(size_t)row * N + col] = acc[mi][ni][r];
        }
      }
    }
  }
}

// ---------------- reduce split partials + bias: out[i] = bias[i%N] + sum_z P[z][i] ----------------
__global__ void reduce_split_bias(const float* __restrict__ P, const float* __restrict__ bias,
                                  float* __restrict__ out, int MN, int N, int Z){
  int i4 = (blockIdx.x * blockDim.x + threadIdx.x) * 4;
  if (i4 >= MN) return;
  const float4 bv = *reinterpret_cast<const float4*>(bias + (i4 % N));
  float4 s = bv;
  for (int z = 0; z < Z; ++z){
    const float4 p = *reinterpret_cast<const float4*>(P + (size_t)z * MN + i4);
    s.x += p.x; s.y += p.y; s.z += p.z; s.w += p.w;
  }
  *reinterpret_cast<float4*>(out + i4) = s;
}

// ---------------- persistent per-sequence LSTM, bf16-packed Whh ----------------
__global__ void lstm_kernel(const float* __restrict__ xp, const unsigned int* __restrict__ Wp,
                            float* __restrict__ out, int S, int H){
  extern __shared__ float sm[];
  float* hv = sm;
  float* cv = sm + H;
  float* gv = sm + 2 * H;
  int b = blockIdx.x;
  int t = threadIdx.x;
  int H4 = 4 * H, H2 = H / 2;
  if (t < H){ hv[t] = 0.f; cv[t] = 0.f; }
  __syncthreads();
  const unsigned int* wp = Wp + t;
  for (int s = 0; s < S; ++s){
    float acc = xp[((size_t)b * S + s) * H4 + t];
    #pragma unroll 4
    for (int j2 = 0; j2 < H2; j2 += 2){
      unsigned int w0 = wp[(size_t)j2 * H4];
      unsigned int w1 = wp[(size_t)(j2 + 1) * H4];
      acc += bf2f_u(w0 & 0xffffu) * hv[2 * j2]
           + bf2f_u(w0 >> 16)     * hv[2 * j2 + 1]
           + bf2f_u(w1 & 0xffffu) * hv[2 * j2 + 2]
           + bf2f_u(w1 >> 16)     * hv[2 * j2 + 3];
    }
    gv[t] = acc;
    __syncthreads();
    if (t < H){
      float ig = sigf(gv[t]);
      float fg = sigf(gv[H + t]);
      float gg = tanhf(gv[2 * H + t]);
      float og = sigf(gv[3 * H + t]);
      float cc = fg * cv[t] + ig * gg;
      cv[t] = cc;
      float hh = og * tanhf(cc);
      hv[t] = hh;
      out[((size_t)b * S + s) * H + t] = hh;
    }
    __syncthreads();
  }
}

// ---------------- per-segment stats over (b,h) ----------------
__global__ void segstats_kernel(const float* __restrict__ lout, int B, int S, int H,
                                float* __restrict__ mean, float* __restrict__ rstd){
  int s = blockIdx.x;
  float sum = 0.f, sum2 = 0.f;
  int cnt = B * H;
  for (int i = threadIdx.x; i < cnt; i += blockDim.x){
    int b = i / H, hh = i % H;
    float v = lout[((size_t)b * S + s) * H + hh];
    sum += v; sum2 += v * v;
  }
  __shared__ float sa[4], sb[4];
  int lane = threadIdx.x & 63, wid = threadIdx.x >> 6;
  for (int off = 32; off; off >>= 1){ sum += __shfl_down(sum, off); sum2 += __shfl_down(sum2, off); }
  if (lane == 0){ sa[wid] = sum; sb[wid] = sum2; }
  __syncthreads();
  if (threadIdx.x == 0){
    sum = sa[0] + sa[1] + sa[2] + sa[3];
    sum2 = sb[0] + sb[1] + sb[2] + sb[3];
    float m = sum / cnt;
    mean[s] = m;
    rstd[s] = rsqrtf(sum2 / cnt - m * m + 1e-5f);
  }
}

// ---------------- bnseg apply + transpose to gcn2 input layout ----------------
__global__ void bnseg_to_g2in_kernel(const float* __restrict__ lout, const float* __restrict__ mean,
                                     const float* __restrict__ rstd, const float* __restrict__ g,
                                     const float* __restrict__ bb, float* __restrict__ g2in,
                                     int B, int S, int H){
  int idx = blockIdx.x * blockDim.x + threadIdx.x;
  int total = B * S * H;
  if (idx >= total) return;
  int hh = idx % H;
  int s = (idx / H) % S;
  int b = idx / (H * S);
  float val = (lout[idx] - mean[s]) * rstd[s] * g[s] + bb[s];
  int nm = b / 25, v = b % 25;
  g2in[((size_t)((nm * H + hh) * S) + s) * 25 + v] = val;
}

// ---------------- support2 -> bf16 A2mat[(nm*S+s)*25+v][k*96+c] ----------------
__global__ void support2_kernel(const float* __restrict__ A, const float* __restrict__ g2in,
                                bf16_t* __restrict__ A2mat, int NM, int C1, int S){
  int idx = blockIdx.x * blockDim.x + threadIdx.x;
  int total = NM * C1 * S * 325;
  if (idx >= total) return;
  int w = idx % 325;
  int s = (idx / 325) % S;
  int c = (idx / (325 * S)) % C1;
  int nm = idx / (325 * S * C1);
  const float* row = g2in + ((size_t)((nm * C1 + c) * S) + s) * 25;
  const float* ar = A + w * 25;
  float acc = 0.f;
  #pragma unroll
  for (int u = 0; u < 25; ++u) acc += ar[u] * row[u];
  int k = w / 25, v = w % 25;
  A2mat[((size_t)((nm * S + s) * 25 + v)) * 1248 + k * C1 + c] = f2bf(acc);
}

// ---------------- bnseg2 + global pool ----------------
__global__ void pool_kernel(const float* __restrict__ lout2, const float* __restrict__ mean,
                            const float* __restrict__ rstd, const float* __restrict__ g,
                            const float* __restrict__ bb, float* __restrict__ pooled,
                            int S, int H){
  int n = blockIdx.x / H;
  int o = blockIdx.x % H;
  float sum = 0.f;
  int cnt = 2 * 25 * S;
  for (int i = threadIdx.x; i < cnt; i += 64){
    int m = i / (25 * S);
    int r = i % (25 * S);
    int v = r / S;
    int s = r % S;
    int b = (n * 2 + m) * 25 + v;
    float val = lout2[((size_t)b * S + s) * H + o];
    val = (val - mean[s]) * rstd[s] * g[s] + bb[s];
    sum += val;
  }
  for (int off = 32; off; off >>= 1) sum += __shfl_down(sum, off);
  if (threadIdx.x == 0) pooled[n * H + o] = sum / cnt;
}

// ---------------- final FC ----------------
__global__ void fc_kernel(const float* __restrict__ pooled, const float* __restrict__ fcW,
                          const float* __restrict__ fcb, float* __restrict__ outp){
  int idx = blockIdx.x * blockDim.x + threadIdx.x;
  if (idx >= 120) return;
  int n = idx / 60, cls = idx % 60;
  float acc = fcb[cls];
  for (int o = 0; o < 192; ++o) acc += pooled[n * 192 + o] * fcW[cls * 192 + o];
  outp[idx] = acc;
}

// ---------------- host: replicate np.linspace + python round (ties-to-even) ----------------
static void make_segs(int T, int S, SegTable& tab, int& L){
  double step = (double)(T - 1) / (double)S;
  long long tv[51];
  for (int i = 0; i <= S; ++i){
    double v = 1.0 + step * (double)i;
    tv[i] = llrint(v);
  }
  L = 0;
  for (int s = 0; s < S; ++s){
    tab.st[s] = (int)tv[s] - 1;
    tab.en[s] = (int)tv[s + 1] - 1;
    int len = tab.en[s] - tab.st[s] + 1;
    if (len > L) L = len;
  }
  for (int s = S; s < 50; ++s){ tab.st[s] = 0; tab.en[s] = 0; }
  if (L > 4) L = 4;
}

extern "C" void kernel_launch(void* const* d_in, const int* in_sizes, int n_in,
                              void* d_out, int out_size, void* d_ws, size_t ws_size,
                              hipStream_t stream){
  const float* x         = (const float*)d_in[0];
  const float* data_bn_g = (const float*)d_in[2];
  const float* data_bn_b = (const float*)d_in[3];
  const float* A_powers1 = (const float*)d_in[4];
  const float* A_res1    = (const float*)d_in[5];
  const float* W1        = (const float*)d_in[6];
  const float* b1        = (const float*)d_in[7];
  const float* bn1_g     = (const float*)d_in[8];
  const float* bn1_b     = (const float*)d_in[9];
  const float* Wih1      = (const float*)d_in[10];
  const float* Whh1      = (const float*)d_in[11];
  const float* bih1      = (const float*)d_in[12];
  const float* bhh1      = (const float*)d_in[13];
  const float* bnseg1_g  = (const float*)d_in[14];
  const float* bnseg1_b  = (const float*)d_in[15];
  const float* A_powers2 = (const float*)d_in[16];
  const float* A_res2    = (const float*)d_in[17];
  const float* W2        = (const float*)d_in[18];
  const float* b2        = (const float*)d_in[19];
  const float* bn2_g     = (const float*)d_in[20];
  const float* bn2_b     = (const float*)d_in[21];
  const float* Wih2      = (const float*)d_in[22];
  const float* Whh2      = (const float*)d_in[23];
  const float* bih2      = (const float*)d_in[24];
  const float* bhh2      = (const float*)d_in[25];
  const float* bnseg2_g  = (const float*)d_in[26];
  const float* bnseg2_b  = (const float*)d_in[27];
  const float* fcW       = (const float*)d_in[28];
  const float* fcb       = (const float*)d_in[29];
  float* out = (float*)d_out;

  const int N = 2, C = 3, T = 100, V = 25, M = 2, NM = 4;
  const int K = 13, C1 = 96, C2 = 192;
  const int S1 = 50, S2 = 30;
  const int B = 100;
  const int IN1 = 4752, IN2 = 18720;
  const int IN1P = 4768;               // K padded to %32
  const int P1 = 4560, P2 = 18336;
  const int KG2 = K * C1;              // 1248, %32 == 0
  const int Z1 = 4, Z2 = 6, ZG = 4;    // split-K factors

  size_t off = 0;
  char* base = (char*)d_ws;
  auto alloc = [&](size_t nbytes) -> void* {
    off = (off + 255) & ~(size_t)255;
    void* p = base + off;
    off += nbytes;
    return p;
  };
  float* A1full = (float*)alloc(325 * 25 * 4);
  float* A2full = (float*)alloc(325 * 25 * 4);
  float* h1     = (float*)alloc((size_t)NM * C * T * V * 4);
  float* sup1   = (float*)alloc((size_t)NM * C * T * 325 * 4);
  float* y1mat  = (float*)alloc((size_t)NM * T * V * C1 * 4);
  float* meanb  = (float*)alloc(1024);
  float* rstdb  = (float*)alloc(1024);
  float* xseq1  = (float*)alloc((size_t)B * T * C1 * 4);
  float* xp1    = (float*)alloc((size_t)B * S1 * 4 * C1 * 4);
  float* l1out  = (float*)alloc((size_t)B * S1 * C1 * 4);
  float* g2in   = (float*)alloc((size_t)NM * C1 * S1 * V * 4);
  bf16_t* A2mat = (bf16_t*)alloc((size_t)NM * S1 * V * KG2 * 2);
  float* y2mat  = (float*)alloc((size_t)NM * S1 * V * C2 * 4);
  float* xseq2  = (float*)alloc((size_t)B * S1 * C2 * 4);
  float* xp2    = (float*)alloc((size_t)B * S2 * 4 * C2 * 4);
  float* l2out  = (float*)alloc((size_t)B * S2 * C2 * 4);
  float* pooled = (float*)alloc(2 * C2 * 4);
  float* bias1  = (float*)alloc(4 * C1 * 4);
  float* bias2  = (float*)alloc(4 * C2 * 4);
  unsigned int* Wp1 = (unsigned int*)alloc((size_t)(C1 / 2) * 4 * C1 * 4);
  unsigned int* Wp2 = (unsigned int*)alloc((size_t)(C2 / 2) * 4 * C2 * 4);
  bf16_t* Wih1b = (bf16_t*)alloc((size_t)4 * C1 * IN1P * 2);
  bf16_t* Wih2b = (bf16_t*)alloc((size_t)4 * C2 * IN2 * 2);
  bf16_t* W2b   = (bf16_t*)alloc((size_t)C2 * KG2 * 2);
  // split partial buffer (reused): max over {Z2*3000*768, Z1*5000*384, ZG*5000*192}
  size_t pmax = (size_t)Z2 * 3000 * 768;
  {
    size_t p1s = (size_t)Z1 * 5000 * 384; if (p1s > pmax) pmax = p1s;
    size_t pgs = (size_t)ZG * 5000 * 192; if (pgs > pmax) pmax = pgs;
  }
  float* Pbuf = (float*)alloc(pmax * 4);
  // shared big buffer: feats1 (5000 x 4768) then feats2 (3000 x 18720), bf16
  bf16_t* feats = (bf16_t*)alloc((size_t)B * S2 * IN2 * 2);
  (void)ws_size; (void)in_sizes; (void)n_in; (void)out_size;

  // constant prep
  vadd_kernel<<<(8125 + 255) / 256, 256, 0, stream>>>(A_powers1, A_res1, A1full, 8125);
  vadd_kernel<<<(8125 + 255) / 256, 256, 0, stream>>>(A_powers2, A_res2, A2full, 8125);
  vadd_kernel<<<2, 256, 0, stream>>>(bih1, bhh1, bias1, 4 * C1);
  vadd_kernel<<<3, 256, 0, stream>>>(bih2, bhh2, bias2, 4 * C2);
  pack_whh_kernel<<<((C1 / 2) * 4 * C1 + 255) / 256, 256, 0, stream>>>(Whh1, Wp1, C1);
  pack_whh_kernel<<<((C2 / 2) * 4 * C2 + 255) / 256, 256, 0, stream>>>(Whh2, Wp2, C2);
  f2bf_pad_kernel<<<(4 * C1 * IN1P + 255) / 256, 256, 0, stream>>>(Wih1, Wih1b, 4 * C1, IN1, IN1P);
  f2bf_pad_kernel<<<(4 * C2 * IN2 + 255) / 256, 256, 0, stream>>>(Wih2, Wih2b, 4 * C2, IN2, IN2);
  f2bf_pad_kernel<<<(C2 * KG2 + 255) / 256, 256, 0, stream>>>(W2, W2b, C2, KG2, KG2);

  // stage 0: data BN
  data_bn_kernel<<<M * V * C, 64, 0, stream>>>(x, data_bn_g, data_bn_b, h1, N, C, T, V, M);

  // stage 1: GCN1
  int tot_sup1 = NM * C * T * 325;
  support1_kernel<<<(tot_sup1 + 255) / 256, 256, 0, stream>>>(A1full, h1, sup1, tot_sup1);
  int tot_y1 = NM * T * 25 * C1;
  gcn1_out_kernel<<<(tot_y1 + 255) / 256, 256, 0, stream>>>(sup1, W1, b1, y1mat, NM, T);
  colstats_kernel<<<C1, 256, 0, stream>>>(y1mat, NM * T * 25, C1, meanb, rstdb);
  bn_relu_seq_kernel<<<(tot_y1 + 255) / 256, 256, 0, stream>>>(y1mat, meanb, rstdb, bn1_g, bn1_b,
                                                               xseq1, NM, T, C1);

  // stage 1: logsig-rnn
  SegTable seg1, seg2; int L1, L2;
  make_segs(T, S1, seg1, L1);
  make_segs(S1, S2, seg2, L2);

  feats_kernel<<<B * S1, 256, 0, stream>>>(xseq1, feats, seg1, T, C1, S1, L1, P1, IN1P);
  {
    int Mm = B * S1, Nn = 4 * C1;
    dim3 g((Mm + 127) / 128, (Nn + 127) / 128, Z1);
    gemm_mfma_nt_split<<<g, 256, 0, stream>>>(feats, Wih1b, Pbuf, Mm, Nn, IN1P);
    int MN = Mm * Nn;
    reduce_split_bias<<<(MN / 4 + 255) / 256, 256, 0, stream>>>(Pbuf, bias1, xp1, MN, Nn, Z1);
  }
  lstm_kernel<<<B, 4 * C1, 6 * C1 * 4, stream>>>(xp1, Wp1, l1out, S1, C1);
  segstats_kernel<<<S1, 256, 0, stream>>>(l1out, B, S1, C1, meanb, rstdb);
  int tot_bn1 = B * S1 * C1;
  bnseg_to_g2in_kernel<<<(tot_bn1 + 255) / 256, 256, 0, stream>>>(l1out, meanb, rstdb, bnseg1_g,
                                                                  bnseg1_b, g2in, B, S1, C1);

  // stage 2: GCN2 (MFMA, split-K)
  int tot_sup2 = NM * C1 * S1 * 325;
  support2_kernel<<<(tot_sup2 + 255) / 256, 256, 0, stream>>>(A2full, g2in, A2mat, NM, C1, S1);
  {
    int Mm = NM * S1 * 25, Nn = C2;
    dim3 g((Mm + 127) / 128, (Nn + 127) / 128, ZG);
    gemm_mfma_nt_split<<<g, 256, 0, stream>>>(A2mat, W2b, Pbuf, Mm, Nn, KG2);
    int MN = Mm * Nn;
    reduce_split_bias<<<(MN / 4 + 255) / 256, 256, 0, stream>>>(Pbuf, b2, y2mat, MN, Nn, ZG);
  }
  colstats_kernel<<<C2, 256, 0, stream>>>(y2mat, NM * S1 * 25, C2, meanb, rstdb);
  int tot_y2 = NM * S1 * 25 * C2;
  bn_relu_seq_kernel<<<(tot_y2 + 255) / 256, 256, 0, stream>>>(y2mat, meanb, rstdb, bn2_g, bn2_b,
                                                               xseq2, NM, S1, C2);

  // stage 2: logsig-rnn
  feats_kernel<<<B * S2, 256, 0, stream>>>(xseq2, feats, seg2, S1, C2, S2, L2, P2, IN2);
  {
    int Mm = B * S2, Nn = 4 * C2;
    dim3 g((Mm + 127) / 128, (Nn + 127) / 128, Z2);
    gemm_mfma_nt_split<<<g, 256, 0, stream>>>(feats, Wih2b, Pbuf, Mm, Nn, IN2);
    int MN = Mm * Nn;
    reduce_split_bias<<<(MN / 4 + 255) / 256, 256, 0, stream>>>(Pbuf, bias2, xp2, MN, Nn, Z2);
  }
  lstm_kernel<<<B, 4 * C2, 6 * C2 * 4, stream>>>(xp2, Wp2, l2out, S2, C2);
  segstats_kernel<<<S2, 256, 0, stream>>>(l2out, B, S2, C2, meanb, rstdb);

  // pool + fc
  pool_kernel<<<2 * C2, 64, 0, stream>>>(l2out, meanb, rstdb, bnseg2_g, bnseg2_b, pooled, S2, C2);
  fc_kernel<<<1, 128, 0, stream>>>(pooled, fcW, fcb, out);
}

// Round 4
// 889.181 us; speedup vs baseline: 3.3602x; 1.1488x over previous
//
#include <hip/hip_runtime.h>
#include <cmath>
#include <cstdint>
#include <cstddef>

typedef unsigned short bf16_t;
typedef __attribute__((ext_vector_type(8))) short short8;
typedef __attribute__((ext_vector_type(4))) float floatx4;
typedef __attribute__((ext_vector_type(2))) _Float16 half2_t;

__device__ __forceinline__ float bf2f(bf16_t b){
  unsigned int u = ((unsigned int)b) << 16;
  return __uint_as_float(u);
}
__device__ __forceinline__ bf16_t f2bf(float f){
  unsigned int u = __float_as_uint(f);
  unsigned int r = (u + 0x7fffu + ((u >> 16) & 1u)) >> 16;  // RNE
  return (bf16_t)r;
}
__device__ __forceinline__ float sigf(float x){ return 1.0f / (1.0f + expf(-x)); }

__device__ __forceinline__ float dot2(half2_t a, half2_t b, float c){
#if __has_builtin(__builtin_amdgcn_fdot2)
  return __builtin_amdgcn_fdot2(a, b, c, false);
#else
  return c + (float)a.x * (float)b.x + (float)a.y * (float)b.y;
#endif
}

__device__ __forceinline__ void gload_lds16(const bf16_t* g, bf16_t* lds){
  __builtin_amdgcn_global_load_lds(
      (const __attribute__((address_space(1))) unsigned int*)g,
      (__attribute__((address_space(3))) unsigned int*)lds, 16, 0, 0);
}

// ---------------- fused tiny adds: A1full, A2full, bias1, bias2 ----------------
__global__ void prep_add_kernel(const float* __restrict__ a1, const float* __restrict__ r1,
                                float* __restrict__ o1,
                                const float* __restrict__ a2, const float* __restrict__ r2,
                                float* __restrict__ o2,
                                const float* __restrict__ bi1, const float* __restrict__ bh1,
                                float* __restrict__ ob1,
                                const float* __restrict__ bi2, const float* __restrict__ bh2,
                                float* __restrict__ ob2){
  int i = blockIdx.x * blockDim.x + threadIdx.x;
  if (i < 8125){ o1[i] = a1[i] + r1[i]; o2[i] = a2[i] + r2[i]; }
  if (i < 384) ob1[i] = bi1[i] + bh1[i];
  if (i < 768) ob2[i] = bi2[i] + bh2[i];
}

// ---------------- fp32 -> bf16 with column zero-padding ----------------
__global__ void f2bf_pad_kernel(const float* __restrict__ in, bf16_t* __restrict__ out,
                                int R, int Kin, int Kout){
  int idx = blockIdx.x * blockDim.x + threadIdx.x;
  int total = R * Kout;
  if (idx >= total) return;
  int r = idx / Kout, k = idx % Kout;
  out[idx] = (k < Kin) ? f2bf(in[(size_t)r * Kin + k]) : (bf16_t)0;
}

// ---------------- pack Whh[t][j] into f16 pairs: Wp[j2*H4+t] = (W[t][2j2],W[t][2j2+1]) ----------------
__global__ void pack_whh_kernel(const float* __restrict__ Whh, half2_t* __restrict__ Wp, int H){
  int H4 = 4 * H, H2 = H / 2;
  int idx = blockIdx.x * blockDim.x + threadIdx.x;
  if (idx >= H4 * H2) return;
  int t = idx % H4, j2 = idx / H4;
  half2_t w;
  w.x = (_Float16)Whh[(size_t)t * H + 2 * j2];
  w.y = (_Float16)Whh[(size_t)t * H + 2 * j2 + 1];
  Wp[idx] = w;
}

// ---------------- LUT: flat pair index -> (i<<8)|j ----------------
__global__ void build_lut_kernel(unsigned short* __restrict__ lut, int d){
  int i = blockIdx.x;            // 0..d-2
  int base = i * (d - 1) - (i * (i - 1)) / 2;
  int rl = d - 1 - i;
  for (int jj = threadIdx.x; jj < rl; jj += blockDim.x)
    lut[base + jj] = (unsigned short)((i << 8) | (i + 1 + jj));
}

// ---------------- data batchnorm: x(N,C,T,V,M) -> h1[(nm*C+c)*T+t][V] ----------------
__global__ void data_bn_kernel(const float* __restrict__ x, const float* __restrict__ g,
                               const float* __restrict__ bb, float* __restrict__ h1,
                               int N, int C, int T, int V, int M){
  int ch = blockIdx.x;             // (m*V + v)*C + c
  int m = ch / (V * C);
  int v = (ch / C) % V;
  int c = ch % C;
  int tid = threadIdx.x;
  int cnt = N * T;
  float s = 0.f, s2 = 0.f;
  for (int i = tid; i < cnt; i += 64){
    int n = i / T, t = i % T;
    float val = x[(((size_t)(n * C + c) * T + t) * V + v) * M + m];
    s += val; s2 += val * val;
  }
  for (int off = 32; off; off >>= 1){ s += __shfl_down(s, off); s2 += __shfl_down(s2, off); }
  s = __shfl(s, 0); s2 = __shfl(s2, 0);
  float mean = s / cnt;
  float rstd = rsqrtf(s2 / cnt - mean * mean + 1e-5f);
  float gg = g[ch], bo = bb[ch];
  for (int i = tid; i < cnt; i += 64){
    int n = i / T, t = i % T;
    float val = x[(((size_t)(n * C + c) * T + t) * V + v) * M + m];
    float y = (val - mean) * rstd * gg + bo;
    h1[((size_t)((n * M + m) * C + c) * T + t) * V + v] = y;
  }
}

// ---------------- support1: sup[row][w] = sum_u A[w][u]*hin[row][u] ----------------
__global__ void support1_kernel(const float* __restrict__ A, const float* __restrict__ hin,
                                float* __restrict__ sup, int total){
  int idx = blockIdx.x * blockDim.x + threadIdx.x;
  if (idx >= total) return;
  int w = idx % 325;
  int rest = idx / 325;
  const float* row = hin + (size_t)rest * 25;
  const float* ar = A + w * 25;
  float acc = 0.f;
  #pragma unroll
  for (int u = 0; u < 25; ++u) acc += ar[u] * row[u];
  sup[idx] = acc;
}

// ---------------- gcn1 output: y1[((nm*T+t)*25+v)*96+o] ----------------
__global__ void gcn1_out_kernel(const float* __restrict__ sup, const float* __restrict__ W1,
                                const float* __restrict__ b1, float* __restrict__ y1, int NM, int T){
  int idx = blockIdx.x * blockDim.x + threadIdx.x;
  int total = NM * T * 25 * 96;
  if (idx >= total) return;
  int o = idx % 96;
  int v = (idx / 96) % 25;
  int t = (idx / (96 * 25)) % T;
  int nm = idx / (96 * 25 * T);
  float acc = b1[o];
  #pragma unroll
  for (int k = 0; k < 13; ++k)
    #pragma unroll
    for (int c = 0; c < 3; ++c)
      acc += W1[o * 39 + k * 3 + c] * sup[(size_t)((nm * 3 + c) * T + t) * 325 + k * 25 + v];
  y1[idx] = acc;
}

// ---------------- per-column stats of mat[R][Cc] ----------------
__global__ void colstats_kernel(const float* __restrict__ mat, int R, int Cc,
                                float* __restrict__ mean, float* __restrict__ rstd){
  int col = blockIdx.x;
  float s = 0.f, s2 = 0.f;
  for (int r = threadIdx.x; r < R; r += blockDim.x){
    float v = mat[(size_t)r * Cc + col]; s += v; s2 += v * v;
  }
  __shared__ float sa[4], sb[4];
  int lane = threadIdx.x & 63, wid = threadIdx.x >> 6;
  for (int off = 32; off; off >>= 1){ s += __shfl_down(s, off); s2 += __shfl_down(s2, off); }
  if (lane == 0){ sa[wid] = s; sb[wid] = s2; }
  __syncthreads();
  if (threadIdx.x == 0){
    s = sa[0] + sa[1] + sa[2] + sa[3];
    s2 = sb[0] + sb[1] + sb[2] + sb[3];
    float m = s / R;
    mean[col] = m;
    rstd[col] = rsqrtf(s2 / R - m * m + 1e-5f);
  }
}

// ---------------- bn + relu + transpose to sequence layout ----------------
__global__ void bn_relu_seq_kernel(const float* __restrict__ ymat, const float* __restrict__ mean,
                                   const float* __restrict__ rstd, const float* __restrict__ g,
                                   const float* __restrict__ bb, float* __restrict__ xseq,
                                   int NM, int T, int H){
  int idx = blockIdx.x * blockDim.x + threadIdx.x;
  int total = NM * T * 25 * H;
  if (idx >= total) return;
  int o = idx % H;
  int v = (idx / H) % 25;
  int t = (idx / (H * 25)) % T;
  int nm = idx / (H * 25 * T);
  float val = (ymat[idx] - mean[o]) * rstd[o] * g[o] + bb[o];
  val = fmaxf(val, 0.f);
  int b = nm * 25 + v;
  xseq[((size_t)b * T + t) * H + o] = val;
}

// ---------------- log-signature features -> bf16 rows (K-padded), LUT-parallel levy ----------------
struct SegTable { int st[50]; int en[50]; };

__global__ void feats_kernel(const float* __restrict__ xseq, bf16_t* __restrict__ feats,
                             SegTable segs, const unsigned short* __restrict__ lut,
                             int T, int d, int S, int L, int pairs, int rowlenP){
  __shared__ float pts[4][192];
  int bs = blockIdx.x;
  int b = bs / S, s = bs % S;
  int st = segs.st[s], en = segs.en[s];
  int nt = blockDim.x, tid = threadIdx.x;
  for (int l = 0; l < L; ++l){
    int t = st + l; if (t > en) t = en;
    for (int i = tid; i < d; i += nt) pts[l][i] = xseq[((size_t)b * T + t) * d + i];
  }
  __syncthreads();
  int rowlen = 2 * d + pairs;
  bf16_t* frow = feats + (size_t)bs * rowlenP;
  for (int i = tid; i < d; i += nt){
    frow[i] = f2bf(pts[0][i]);
    frow[d + i] = f2bf(pts[L - 1][i] - pts[0][i]);
  }
  for (int i = tid + rowlen; i < rowlenP; i += nt) frow[i] = 0;  // K pad
  int Lm2 = L - 2;
  bf16_t* lrow = frow + 2 * d;
  for (int p = tid; p < pairs; p += nt){
    int e = lut[p];
    int i = e >> 8, j = e & 255;
    float acc = 0.f;
    for (int l = 1; l <= Lm2; ++l){
      float ri = pts[l][i] - pts[0][i], rj = pts[l][j] - pts[0][j];
      float di = pts[l + 1][i] - pts[l][i], dj = pts[l + 1][j] - pts[l][j];
      acc += ri * dj - rj * di;
    }
    lrow[p] = f2bf(0.5f * acc);
  }
}

// ---------------- split-K MFMA bf16 NT GEMM: P[z] = A[M][K_z] * B[N][K_z]^T ----------------
__global__ __launch_bounds__(256)
void gemm_mfma_nt_split(const bf16_t* __restrict__ A, const bf16_t* __restrict__ B,
                        float* __restrict__ P, int M, int N, int K){
  __shared__ bf16_t As[128 * 32];
  __shared__ bf16_t Bs[128 * 32];
  const int tid = threadIdx.x;
  const int lane = tid & 63, wv = tid >> 6;
  const int bm = blockIdx.x * 128, bn = blockIdx.y * 128;
  const int wr = (wv >> 1) * 64, wc = (wv & 1) * 64;
  const int m_l = lane & 15, q = lane >> 4;

  const int ksteps = K >> 5;
  const int Z = gridDim.z, z = blockIdx.z;
  const int per = (ksteps + Z - 1) / Z;
  const int ks0 = z * per;
  const int ks1 = (ks0 + per < ksteps) ? ks0 + per : ksteps;

  const bf16_t* gA[2]; const bf16_t* gB[2];
  bf16_t* lA[2]; bf16_t* lB[2];
  #pragma unroll
  for (int it = 0; it < 2; ++it){
    int c = it * 4 + wv;
    int rowA = bm + c * 16 + (lane >> 2);
    if (rowA > M - 1) rowA = M - 1;
    int rowB = bn + c * 16 + (lane >> 2);
    if (rowB > N - 1) rowB = N - 1;
    int col = (lane & 3) * 8;
    gA[it] = A + (size_t)rowA * K + col;
    gB[it] = B + (size_t)rowB * K + col;
    lA[it] = &As[c * 512];
    lB[it] = &Bs[c * 512];
  }
  const bf16_t* pa[4]; const bf16_t* pb[4];
  #pragma unroll
  for (int i = 0; i < 4; ++i){
    pa[i] = &As[(wr + i * 16 + m_l) * 32 + q * 8];
    pb[i] = &Bs[(wc + i * 16 + m_l) * 32 + q * 8];
  }

  floatx4 acc[4][4] = {};
  for (int ks = ks0; ks < ks1; ++ks){
    int k0 = ks << 5;
    __syncthreads();
    gload_lds16(gA[0] + k0, lA[0]);
    gload_lds16(gA[1] + k0, lA[1]);
    gload_lds16(gB[0] + k0, lB[0]);
    gload_lds16(gB[1] + k0, lB[1]);
    __syncthreads();
    short8 af[4], bfr[4];
    #pragma unroll
    for (int i = 0; i < 4; ++i){
      af[i]  = *reinterpret_cast<const short8*>(pa[i]);
      bfr[i] = *reinterpret_cast<const short8*>(pb[i]);
    }
    #pragma unroll
    for (int mi = 0; mi < 4; ++mi)
      #pragma unroll
      for (int ni = 0; ni < 4; ++ni)
        acc[mi][ni] = __builtin_amdgcn_mfma_f32_16x16x32_bf16(af[mi], bfr[ni], acc[mi][ni], 0, 0, 0);
  }

  float* Pz = P + (size_t)z * M * N;
  #pragma unroll
  for (int mi = 0; mi < 4; ++mi){
    int row0 = bm + wr + mi * 16 + q * 4;
    #pragma unroll
    for (int r = 0; r < 4; ++r){
      int row = row0 + r;
      if (row < M){
        #pragma unroll
        for (int ni = 0; ni < 4; ++ni){
          int col = bn + wc + ni * 16 + m_l;
          if (col < N) Pz[(size_t)row * N + col] = acc[mi][ni][r];
        }
      }
    }
  }
}

// ---------------- reduce split partials + bias (GCN2 path) ----------------
__global__ void reduce_split_bias(const float* __restrict__ P, const float* __restrict__ bias,
                                  float* __restrict__ out, int MN, int N, int Z){
  int i4 = (blockIdx.x * blockDim.x + threadIdx.x) * 4;
  if (i4 >= MN) return;
  const float4 bv = *reinterpret_cast<const float4*>(bias + (i4 % N));
  float4 s = bv;
  for (int z = 0; z < Z; ++z){
    const float4 p = *reinterpret_cast<const float4*>(P + (size_t)z * MN + i4);
    s.x += p.x; s.y += p.y; s.z += p.z; s.w += p.w;
  }
  *reinterpret_cast<float4*>(out + i4) = s;
}

// ---------------- persistent per-sequence LSTM: register f16 weights, fused split-K reduce ----------------
template <int H2C, int BLK>
__global__ __launch_bounds__(BLK)
void lstm_kernel(const float* __restrict__ P, const float* __restrict__ bias,
                 const half2_t* __restrict__ Wp, float* __restrict__ out,
                 int S, int MN, int Z){
  constexpr int H = 2 * H2C;
  constexpr int H4 = 4 * H;
  __shared__ _Float16 __attribute__((aligned(16))) hsh[H];
  __shared__ float gv[H4];
  const int b = blockIdx.x, t = threadIdx.x;
  half2_t w[H2C];
  const half2_t* wp = Wp + t;
  #pragma unroll
  for (int j2 = 0; j2 < H2C; ++j2) w[j2] = wp[(size_t)j2 * H4];
  float cc = 0.f;
  if (t < H) hsh[t] = (_Float16)0.f;
  const float bval = bias[t];
  __syncthreads();
  const half2_t* hp = reinterpret_cast<const half2_t*>(hsh);
  for (int s = 0; s < S; ++s){
    size_t rowoff = ((size_t)b * S + s) * H4 + t;
    float acc = bval;
    for (int z = 0; z < Z; ++z) acc += P[(size_t)z * MN + rowoff];
    #pragma unroll
    for (int j2 = 0; j2 < H2C; ++j2) acc = dot2(w[j2], hp[j2], acc);
    gv[t] = acc;
    __syncthreads();
    if (t < H){
      float ig = sigf(gv[t]);
      float fg = sigf(gv[H + t]);
      float gg = tanhf(gv[2 * H + t]);
      float og = sigf(gv[3 * H + t]);
      cc = fg * cc + ig * gg;
      float hh = og * tanhf(cc);
      hsh[t] = (_Float16)hh;
      out[((size_t)b * S + s) * H + t] = hh;
    }
    __syncthreads();
  }
}

// ---------------- per-segment stats over (b,h) ----------------
__global__ void segstats_kernel(const float* __restrict__ lout, int B, int S, int H,
                                float* __restrict__ mean, float* __restrict__ rstd){
  int s = blockIdx.x;
  float sum = 0.f, sum2 = 0.f;
  int cnt = B * H;
  for (int i = threadIdx.x; i < cnt; i += blockDim.x){
    int b = i / H, hh = i % H;
    float v = lout[((size_t)b * S + s) * H + hh];
    sum += v; sum2 += v * v;
  }
  __shared__ float sa[4], sb[4];
  int lane = threadIdx.x & 63, wid = threadIdx.x >> 6;
  for (int off = 32; off; off >>= 1){ sum += __shfl_down(sum, off); sum2 += __shfl_down(sum2, off); }
  if (lane == 0){ sa[wid] = sum; sb[wid] = sum2; }
  __syncthreads();
  if (threadIdx.x == 0){
    sum = sa[0] + sa[1] + sa[2] + sa[3];
    sum2 = sb[0] + sb[1] + sb[2] + sb[3];
    float m = sum / cnt;
    mean[s] = m;
    rstd[s] = rsqrtf(sum2 / cnt - m * m + 1e-5f);
  }
}

// ---------------- bnseg apply + transpose to gcn2 input layout ----------------
__global__ void bnseg_to_g2in_kernel(const float* __restrict__ lout, const float* __restrict__ mean,
                                     const float* __restrict__ rstd, const float* __restrict__ g,
                                     const float* __restrict__ bb, float* __restrict__ g2in,
                                     int B, int S, int H){
  int idx = blockIdx.x * blockDim.x + threadIdx.x;
  int total = B * S * H;
  if (idx >= total) return;
  int hh = idx % H;
  int s = (idx / H) % S;
  int b = idx / (H * S);
  float val = (lout[idx] - mean[s]) * rstd[s] * g[s] + bb[s];
  int nm = b / 25, v = b % 25;
  g2in[((size_t)((nm * H + hh) * S) + s) * 25 + v] = val;
}

// ---------------- support2 -> bf16 A2mat[(nm*S+s)*25+v][k*96+c] ----------------
__global__ void support2_kernel(const float* __restrict__ A, const float* __restrict__ g2in,
                                bf16_t* __restrict__ A2mat, int NM, int C1, int S){
  int idx = blockIdx.x * blockDim.x + threadIdx.x;
  int total = NM * C1 * S * 325;
  if (idx >= total) return;
  int w = idx % 325;
  int s = (idx / 325) % S;
  int c = (idx / (325 * S)) % C1;
  int nm = idx / (325 * S * C1);
  const float* row = g2in + ((size_t)((nm * C1 + c) * S) + s) * 25;
  const float* ar = A + w * 25;
  float acc = 0.f;
  #pragma unroll
  for (int u = 0; u < 25; ++u) acc += ar[u] * row[u];
  int k = w / 25, v = w % 25;
  A2mat[((size_t)((nm * S + s) * 25 + v)) * 1248 + k * C1 + c] = f2bf(acc);
}

// ---------------- bnseg2 + global pool ----------------
__global__ void pool_kernel(const float* __restrict__ lout2, const float* __restrict__ mean,
                            const float* __restrict__ rstd, const float* __restrict__ g,
                            const float* __restrict__ bb, float* __restrict__ pooled,
                            int S, int H){
  int n = blockIdx.x / H;
  int o = blockIdx.x % H;
  float sum = 0.f;
  int cnt = 2 * 25 * S;
  for (int i = threadIdx.x; i < cnt; i += 64){
    int m = i / (25 * S);
    int r = i % (25 * S);
    int v = r / S;
    int s = r % S;
    int b = (n * 2 + m) * 25 + v;
    float val = lout2[((size_t)b * S + s) * H + o];
    val = (val - mean[s]) * rstd[s] * g[s] + bb[s];
    sum += val;
  }
  for (int off = 32; off; off >>= 1) sum += __shfl_down(sum, off);
  if (threadIdx.x == 0) pooled[n * H + o] = sum / cnt;
}

// ---------------- final FC ----------------
__global__ void fc_kernel(const float* __restrict__ pooled, const float* __restrict__ fcW,
                          const float* __restrict__ fcb, float* __restrict__ outp){
  int idx = blockIdx.x * blockDim.x + threadIdx.x;
  if (idx >= 120) return;
  int n = idx / 60, cls = idx % 60;
  float acc = fcb[cls];
  for (int o = 0; o < 192; ++o) acc += pooled[n * 192 + o] * fcW[cls * 192 + o];
  outp[idx] = acc;
}

// ---------------- host: replicate np.linspace + python round (ties-to-even) ----------------
static void make_segs(int T, int S, SegTable& tab, int& L){
  double step = (double)(T - 1) / (double)S;
  long long tv[51];
  for (int i = 0; i <= S; ++i){
    double v = 1.0 + step * (double)i;
    tv[i] = llrint(v);
  }
  L = 0;
  for (int s = 0; s < S; ++s){
    tab.st[s] = (int)tv[s] - 1;
    tab.en[s] = (int)tv[s + 1] - 1;
    int len = tab.en[s] - tab.st[s] + 1;
    if (len > L) L = len;
  }
  for (int s = S; s < 50; ++s){ tab.st[s] = 0; tab.en[s] = 0; }
  if (L > 4) L = 4;
}

extern "C" void kernel_launch(void* const* d_in, const int* in_sizes, int n_in,
                              void* d_out, int out_size, void* d_ws, size_t ws_size,
                              hipStream_t stream){
  const float* x         = (const float*)d_in[0];
  const float* data_bn_g = (const float*)d_in[2];
  const float* data_bn_b = (const float*)d_in[3];
  const float* A_powers1 = (const float*)d_in[4];
  const float* A_res1    = (const float*)d_in[5];
  const float* W1        = (const float*)d_in[6];
  const float* b1        = (const float*)d_in[7];
  const float* bn1_g     = (const float*)d_in[8];
  const float* bn1_b     = (const float*)d_in[9];
  const float* Wih1      = (const float*)d_in[10];
  const float* Whh1      = (const float*)d_in[11];
  const float* bih1      = (const float*)d_in[12];
  const float* bhh1      = (const float*)d_in[13];
  const float* bnseg1_g  = (const float*)d_in[14];
  const float* bnseg1_b  = (const float*)d_in[15];
  const float* A_powers2 = (const float*)d_in[16];
  const float* A_res2    = (const float*)d_in[17];
  const float* W2        = (const float*)d_in[18];
  const float* b2        = (const float*)d_in[19];
  const float* bn2_g     = (const float*)d_in[20];
  const float* bn2_b     = (const float*)d_in[21];
  const float* Wih2      = (const float*)d_in[22];
  const float* Whh2      = (const float*)d_in[23];
  const float* bih2      = (const float*)d_in[24];
  const float* bhh2      = (const float*)d_in[25];
  const float* bnseg2_g  = (const float*)d_in[26];
  const float* bnseg2_b  = (const float*)d_in[27];
  const float* fcW       = (const float*)d_in[28];
  const float* fcb       = (const float*)d_in[29];
  float* out = (float*)d_out;

  const int N = 2, C = 3, T = 100, V = 25, M = 2, NM = 4;
  const int K = 13, C1 = 96, C2 = 192;
  const int S1 = 50, S2 = 30;
  const int B = 100;
  const int IN1 = 4752, IN2 = 18720;
  const int IN1P = 4768;               // K padded to %32
  const int P1 = 4560, P2 = 18336;
  const int KG2 = K * C1;              // 1248
  const int Z1 = 6, Z2 = 8, ZG = 4;    // split-K factors

  size_t off = 0;
  char* base = (char*)d_ws;
  auto alloc = [&](size_t nbytes) -> void* {
    off = (off + 255) & ~(size_t)255;
    void* p = base + off;
    off += nbytes;
    return p;
  };
  float* A1full = (float*)alloc(325 * 25 * 4);
  float* A2full = (float*)alloc(325 * 25 * 4);
  float* h1     = (float*)alloc((size_t)NM * C * T * V * 4);
  float* sup1   = (float*)alloc((size_t)NM * C * T * 325 * 4);
  float* y1mat  = (float*)alloc((size_t)NM * T * V * C1 * 4);
  float* meanb  = (float*)alloc(1024);
  float* rstdb  = (float*)alloc(1024);
  float* xseq1  = (float*)alloc((size_t)B * T * C1 * 4);
  float* l1out  = (float*)alloc((size_t)B * S1 * C1 * 4);
  float* g2in   = (float*)alloc((size_t)NM * C1 * S1 * V * 4);
  bf16_t* A2mat = (bf16_t*)alloc((size_t)NM * S1 * V * KG2 * 2);
  float* y2mat  = (float*)alloc((size_t)NM * S1 * V * C2 * 4);
  float* xseq2  = (float*)alloc((size_t)B * S1 * C2 * 4);
  float* l2out  = (float*)alloc((size_t)B * S2 * C2 * 4);
  float* pooled = (float*)alloc(2 * C2 * 4);
  float* bias1  = (float*)alloc(4 * C1 * 4);
  float* bias2  = (float*)alloc(4 * C2 * 4);
  half2_t* Wp1  = (half2_t*)alloc((size_t)(C1 / 2) * 4 * C1 * 4);
  half2_t* Wp2  = (half2_t*)alloc((size_t)(C2 / 2) * 4 * C2 * 4);
  bf16_t* Wih1b = (bf16_t*)alloc((size_t)4 * C1 * IN1P * 2);
  bf16_t* Wih2b = (bf16_t*)alloc((size_t)4 * C2 * IN2 * 2);
  bf16_t* W2b   = (bf16_t*)alloc((size_t)C2 * KG2 * 2);
  unsigned short* lut1 = (unsigned short*)alloc((size_t)P1 * 2);
  unsigned short* lut2 = (unsigned short*)alloc((size_t)P2 * 2);
  // split partial buffer (reused): max over {Z2*3000*768, Z1*5000*384, ZG*5000*192}
  size_t pmax = (size_t)Z2 * 3000 * 768;
  {
    size_t p1s = (size_t)Z1 * 5000 * 384; if (p1s > pmax) pmax = p1s;
    size_t pgs = (size_t)ZG * 5000 * 192; if (pgs > pmax) pmax = pgs;
  }
  float* Pbuf = (float*)alloc(pmax * 4);
  bf16_t* feats = (bf16_t*)alloc((size_t)B * S2 * IN2 * 2);
  (void)ws_size; (void)in_sizes; (void)n_in; (void)out_size;

  // constant prep
  prep_add_kernel<<<32, 256, 0, stream>>>(A_powers1, A_res1, A1full, A_powers2, A_res2, A2full,
                                          bih1, bhh1, bias1, bih2, bhh2, bias2);
  pack_whh_kernel<<<((C1 / 2) * 4 * C1 + 255) / 256, 256, 0, stream>>>(Whh1, Wp1, C1);
  pack_whh_kernel<<<((C2 / 2) * 4 * C2 + 255) / 256, 256, 0, stream>>>(Whh2, Wp2, C2);
  f2bf_pad_kernel<<<(4 * C1 * IN1P + 255) / 256, 256, 0, stream>>>(Wih1, Wih1b, 4 * C1, IN1, IN1P);
  f2bf_pad_kernel<<<(4 * C2 * IN2 + 255) / 256, 256, 0, stream>>>(Wih2, Wih2b, 4 * C2, IN2, IN2);
  f2bf_pad_kernel<<<(C2 * KG2 + 255) / 256, 256, 0, stream>>>(W2, W2b, C2, KG2, KG2);
  build_lut_kernel<<<C1 - 1, 64, 0, stream>>>(lut1, C1);
  build_lut_kernel<<<C2 - 1, 64, 0, stream>>>(lut2, C2);

  // stage 0: data BN
  data_bn_kernel<<<M * V * C, 64, 0, stream>>>(x, data_bn_g, data_bn_b, h1, N, C, T, V, M);

  // stage 1: GCN1
  int tot_sup1 = NM * C * T * 325;
  support1_kernel<<<(tot_sup1 + 255) / 256, 256, 0, stream>>>(A1full, h1, sup1, tot_sup1);
  int tot_y1 = NM * T * 25 * C1;
  gcn1_out_kernel<<<(tot_y1 + 255) / 256, 256, 0, stream>>>(sup1, W1, b1, y1mat, NM, T);
  colstats_kernel<<<C1, 256, 0, stream>>>(y1mat, NM * T * 25, C1, meanb, rstdb);
  bn_relu_seq_kernel<<<(tot_y1 + 255) / 256, 256, 0, stream>>>(y1mat, meanb, rstdb, bn1_g, bn1_b,
                                                               xseq1, NM, T, C1);

  // stage 1: logsig-rnn
  SegTable seg1, seg2; int L1, L2;
  make_segs(T, S1, seg1, L1);
  make_segs(S1, S2, seg2, L2);

  feats_kernel<<<B * S1, 256, 0, stream>>>(xseq1, feats, seg1, lut1, T, C1, S1, L1, P1, IN1P);
  {
    int Mm = B * S1, Nn = 4 * C1;
    dim3 g((Mm + 127) / 128, (Nn + 127) / 128, Z1);
    gemm_mfma_nt_split<<<g, 256, 0, stream>>>(feats, Wih1b, Pbuf, Mm, Nn, IN1P);
    lstm_kernel<48, 384><<<B, 384, 0, stream>>>(Pbuf, bias1, Wp1, l1out, S1, Mm * Nn, Z1);
  }
  segstats_kernel<<<S1, 256, 0, stream>>>(l1out, B, S1, C1, meanb, rstdb);
  int tot_bn1 = B * S1 * C1;
  bnseg_to_g2in_kernel<<<(tot_bn1 + 255) / 256, 256, 0, stream>>>(l1out, meanb, rstdb, bnseg1_g,
                                                                  bnseg1_b, g2in, B, S1, C1);

  // stage 2: GCN2 (MFMA, split-K)
  int tot_sup2 = NM * C1 * S1 * 325;
  support2_kernel<<<(tot_sup2 + 255) / 256, 256, 0, stream>>>(A2full, g2in, A2mat, NM, C1, S1);
  {
    int Mm = NM * S1 * 25, Nn = C2;
    dim3 g((Mm + 127) / 128, (Nn + 127) / 128, ZG);
    gemm_mfma_nt_split<<<g, 256, 0, stream>>>(A2mat, W2b, Pbuf, Mm, Nn, KG2);
    int MN = Mm * Nn;
    reduce_split_bias<<<(MN / 4 + 255) / 256, 256, 0, stream>>>(Pbuf, b2, y2mat, MN, Nn, ZG);
  }
  colstats_kernel<<<C2, 256, 0, stream>>>(y2mat, NM * S1 * 25, C2, meanb, rstdb);
  int tot_y2 = NM * S1 * 25 * C2;
  bn_relu_seq_kernel<<<(tot_y2 + 255) / 256, 256, 0, stream>>>(y2mat, meanb, rstdb, bn2_g, bn2_b,
                                                               xseq2, NM, S1, C2);

  // stage 2: logsig-rnn
  feats_kernel<<<B * S2, 256, 0, stream>>>(xseq2, feats, seg2, lut2, S1, C2, S2, L2, P2, IN2);
  {
    int Mm = B * S2, Nn = 4 * C2;
    dim3 g((Mm + 127) / 128, (Nn + 127) / 128, Z2);
    gemm_mfma_nt_split<<<g, 256, 0, stream>>>(feats, Wih2b, Pbuf, Mm, Nn, IN2);
    lstm_kernel<96, 768><<<B, 768, 0, stream>>>(Pbuf, bias2, Wp2, l2out, S2, Mm * Nn, Z2);
  }
  segstats_kernel<<<S2, 256, 0, stream>>>(l2out, B, S2, C2, meanb, rstdb);

  // pool + fc
  pool_kernel<<<2 * C2, 64, 0, stream>>>(l2out, meanb, rstdb, bnseg2_g, bnseg2_b, pooled, S2, C2);
  fc_kernel<<<1, 128, 0, stream>>>(pooled, fcW, fcb, out);
}

// Round 5
// 764.170 us; speedup vs baseline: 3.9099x; 1.1636x over previous
//
#include <hip/hip_runtime.h>
#include <cmath>
#include <cstdint>
#include <cstddef>

typedef unsigned short bf16_t;
typedef __attribute__((ext_vector_type(8))) short short8;
typedef __attribute__((ext_vector_type(4))) float floatx4;
typedef __attribute__((ext_vector_type(2))) _Float16 half2_t;

__device__ __forceinline__ float bf2f(bf16_t b){
  unsigned int u = ((unsigned int)b) << 16;
  return __uint_as_float(u);
}
__device__ __forceinline__ bf16_t f2bf(float f){
  unsigned int u = __float_as_uint(f);
  unsigned int r = (u + 0x7fffu + ((u >> 16) & 1u)) >> 16;  // RNE
  return (bf16_t)r;
}
__device__ __forceinline__ unsigned int f2bf2(float a, float b){
  return (unsigned int)f2bf(a) | ((unsigned int)f2bf(b) << 16);
}
__device__ __forceinline__ float sigf(float x){ return 1.0f / (1.0f + expf(-x)); }

__device__ __forceinline__ float dot2(half2_t a, half2_t b, float c){
#if __has_builtin(__builtin_amdgcn_fdot2)
  return __builtin_amdgcn_fdot2(a, b, c, false);
#else
  return c + (float)a.x * (float)b.x + (float)a.y * (float)b.y;
#endif
}

__device__ __forceinline__ void gload_lds16(const bf16_t* g, bf16_t* lds){
  __builtin_amdgcn_global_load_lds(
      (const __attribute__((address_space(1))) unsigned int*)g,
      (__attribute__((address_space(3))) unsigned int*)lds, 16, 0, 0);
}

// ---------------- mega prep kernel: adds, whh pack, LUTs, stat zero, A2mat K-pad ----------------
__global__ void prep_misc(const float* __restrict__ a1, const float* __restrict__ r1, float* __restrict__ o1,
                          const float* __restrict__ a2, const float* __restrict__ r2, float* __restrict__ o2,
                          const float* __restrict__ bi1, const float* __restrict__ bh1, float* __restrict__ ob1,
                          const float* __restrict__ bi2, const float* __restrict__ bh2, float* __restrict__ ob2,
                          const float* __restrict__ Whh1, half2_t* __restrict__ Wp1,
                          const float* __restrict__ Whh2, half2_t* __restrict__ Wp2,
                          unsigned short* __restrict__ lut1, unsigned short* __restrict__ lut2,
                          float* __restrict__ stats, bf16_t* __restrict__ A2mat){
  int i = blockIdx.x * blockDim.x + threadIdx.x;
  if (i < 8125){ o1[i] = a1[i] + r1[i]; o2[i] = a2[i] + r2[i]; }
  if (i < 384) ob1[i] = bi1[i] + bh1[i];
  if (i < 768) ob2[i] = bi2[i] + bh2[i];
  if (i < 736) stats[i] = 0.f;
  if (i < 18432){                       // pack Whh1 (H=96): Wp[j2*384+t]
    int t = i % 384, j2 = i / 384;
    half2_t w; w.x = (_Float16)Whh1[(size_t)t * 96 + 2 * j2];
    w.y = (_Float16)Whh1[(size_t)t * 96 + 2 * j2 + 1];
    Wp1[i] = w;
  }
  if (i < 73728){                       // pack Whh2 (H=192)
    int t = i % 768, j2 = i / 768;
    half2_t w; w.x = (_Float16)Whh2[(size_t)t * 192 + 2 * j2];
    w.y = (_Float16)Whh2[(size_t)t * 192 + 2 * j2 + 1];
    Wp2[i] = w;
  }
  // levy pair LUTs: flat p -> (i<<8)|j
  if (i < 4560){
    int d = 96, p = i;
    int r = (int)(((2.0 * d - 1.0) - sqrt((2.0 * d - 1.0) * (2.0 * d - 1.0) - 8.0 * (double)p)) * 0.5);
    if (r < 0) r = 0;
    while (r + 1 <= d - 2 && (r + 1) * (d - 1) - ((r + 1) * r) / 2 <= p) ++r;
    while (r > 0 && r * (d - 1) - (r * (r - 1)) / 2 > p) --r;
    int jj = p - (r * (d - 1) - (r * (r - 1)) / 2);
    lut1[p] = (unsigned short)((r << 8) | (r + 1 + jj));
  }
  if (i < 18336){
    int d = 192, p = i;
    int r = (int)(((2.0 * d - 1.0) - sqrt((2.0 * d - 1.0) * (2.0 * d - 1.0) - 8.0 * (double)p)) * 0.5);
    if (r < 0) r = 0;
    while (r + 1 <= d - 2 && (r + 1) * (d - 1) - ((r + 1) * r) / 2 <= p) ++r;
    while (r > 0 && r * (d - 1) - (r * (r - 1)) / 2 > p) --r;
    int jj = p - (r * (d - 1) - (r * (r - 1)) / 2);
    lut2[p] = (unsigned short)((r << 8) | (r + 1 + jj));
  }
  if (i < 160000){                      // A2mat K-pad cols [1248,1280), 5000 rows
    int row = i >> 5, col = 1248 + (i & 31);
    A2mat[(size_t)row * 1280 + col] = 0;
  }
}

// ---------------- fp32 -> bf16, 8-wide, column zero-padding (Kin%8==0, Kout%8==0) ----------------
__global__ void f2bf_pad8(const float* __restrict__ in, bf16_t* __restrict__ out,
                          int R, int Kin, int Kout){
  int idx = blockIdx.x * blockDim.x + threadIdx.x;
  int ko8 = Kout >> 3;
  if (idx >= R * ko8) return;
  int r = idx / ko8, k8 = (idx % ko8) << 3;
  uint4 u;
  if (k8 + 8 <= Kin){
    const float4* p = reinterpret_cast<const float4*>(in + (size_t)r * Kin + k8);
    float4 x0 = p[0], x1 = p[1];
    u.x = f2bf2(x0.x, x0.y); u.y = f2bf2(x0.z, x0.w);
    u.z = f2bf2(x1.x, x1.y); u.w = f2bf2(x1.z, x1.w);
  } else {
    u.x = u.y = u.z = u.w = 0u;
  }
  *reinterpret_cast<uint4*>(out + (size_t)r * Kout + k8) = u;
}

// ---------------- data batchnorm: x(N,C,T,V,M) -> h1[(nm*C+c)*T+t][V] ----------------
__global__ void data_bn_kernel(const float* __restrict__ x, const float* __restrict__ g,
                               const float* __restrict__ bb, float* __restrict__ h1,
                               int N, int C, int T, int V, int M){
  int ch = blockIdx.x;             // (m*V + v)*C + c
  int m = ch / (V * C);
  int v = (ch / C) % V;
  int c = ch % C;
  int tid = threadIdx.x;
  int cnt = N * T;
  float s = 0.f, s2 = 0.f;
  for (int i = tid; i < cnt; i += 64){
    int n = i / T, t = i % T;
    float val = x[(((size_t)(n * C + c) * T + t) * V + v) * M + m];
    s += val; s2 += val * val;
  }
  for (int off = 32; off; off >>= 1){ s += __shfl_down(s, off); s2 += __shfl_down(s2, off); }
  s = __shfl(s, 0); s2 = __shfl(s2, 0);
  float mean = s / cnt;
  float rstd = rsqrtf(s2 / cnt - mean * mean + 1e-5f);
  float gg = g[ch], bo = bb[ch];
  for (int i = tid; i < cnt; i += 64){
    int n = i / T, t = i % T;
    float val = x[(((size_t)(n * C + c) * T + t) * V + v) * M + m];
    float y = (val - mean) * rstd * gg + bo;
    h1[((size_t)((n * M + m) * C + c) * T + t) * V + v] = y;
  }
}

// ---------------- support1: sup[row][w] = sum_u A[w][u]*hin[row][u] ----------------
__global__ void support1_kernel(const float* __restrict__ A, const float* __restrict__ hin,
                                float* __restrict__ sup, int total){
  int idx = blockIdx.x * blockDim.x + threadIdx.x;
  if (idx >= total) return;
  int w = idx % 325;
  int rest = idx / 325;
  const float* row = hin + (size_t)rest * 25;
  const float* ar = A + w * 25;
  float acc = 0.f;
  #pragma unroll
  for (int u = 0; u < 25; ++u) acc += ar[u] * row[u];
  sup[idx] = acc;
}

// ---------------- gcn1 output: y1[((nm*T+t)*25+v)*96+o] ----------------
__global__ void gcn1_out_kernel(const float* __restrict__ sup, const float* __restrict__ W1,
                                const float* __restrict__ b1, float* __restrict__ y1, int NM, int T){
  int idx = blockIdx.x * blockDim.x + threadIdx.x;
  int total = NM * T * 25 * 96;
  if (idx >= total) return;
  int o = idx % 96;
  int v = (idx / 96) % 25;
  int t = (idx / (96 * 25)) % T;
  int nm = idx / (96 * 25 * T);
  float acc = b1[o];
  #pragma unroll
  for (int k = 0; k < 13; ++k)
    #pragma unroll
    for (int c = 0; c < 3; ++c)
      acc += W1[o * 39 + k * 3 + c] * sup[(size_t)((nm * 3 + c) * T + t) * 325 + k * 25 + v];
  y1[idx] = acc;
}

// ---------------- coalesced column-stat accumulate (blockDim == Cc) ----------------
__global__ void colstats_atomic(const float* __restrict__ mat, int R,
                                float* __restrict__ sum, float* __restrict__ sumsq){
  int col = threadIdx.x;
  int Cc = blockDim.x;
  float s = 0.f, s2 = 0.f;
  for (int r = blockIdx.x; r < R; r += gridDim.x){
    float v = mat[(size_t)r * Cc + col];
    s += v; s2 += v * v;
  }
  atomicAdd(&sum[col], s);
  atomicAdd(&sumsq[col], s2);
}

// ---------------- coalesced per-segment stat accumulate (blockDim == H) ----------------
__global__ void segstats_atomic(const float* __restrict__ lout, int R2, int S,
                                float* __restrict__ sum, float* __restrict__ sumsq){
  int t = threadIdx.x;
  int H = blockDim.x;
  int nw = H >> 6;
  __shared__ float ra[4], rb[4];
  int lane = t & 63, wid = t >> 6;
  for (int r = blockIdx.x; r < R2; r += gridDim.x){
    int s = r % S;
    float v = lout[(size_t)r * H + t];
    float a = v, b2 = v * v;
    for (int off = 32; off; off >>= 1){ a += __shfl_down(a, off); b2 += __shfl_down(b2, off); }
    if (lane == 0){ ra[wid] = a; rb[wid] = b2; }
    __syncthreads();
    if (t == 0){
      float sa = 0.f, sb = 0.f;
      for (int w = 0; w < nw; ++w){ sa += ra[w]; sb += rb[w]; }
      atomicAdd(&sum[s], sa);
      atomicAdd(&sumsq[s], sb);
    }
    __syncthreads();
  }
}

// ---------------- bn (from sums) + relu + transpose to sequence layout ----------------
__global__ void bn_relu_seq_kernel(const float* __restrict__ ymat, const float* __restrict__ sum,
                                   const float* __restrict__ sumsq, const float* __restrict__ g,
                                   const float* __restrict__ bb, float* __restrict__ xseq,
                                   int NM, int T, int H, int R){
  int idx = blockIdx.x * blockDim.x + threadIdx.x;
  int total = NM * T * 25 * H;
  if (idx >= total) return;
  int o = idx % H;
  int v = (idx / H) % 25;
  int t = (idx / (H * 25)) % T;
  int nm = idx / (H * 25 * T);
  float mean = sum[o] / R;
  float rstd = rsqrtf(sumsq[o] / R - mean * mean + 1e-5f);
  float val = (ymat[idx] - mean) * rstd * g[o] + bb[o];
  val = fmaxf(val, 0.f);
  int b = nm * 25 + v;
  xseq[((size_t)b * T + t) * H + o] = val;
}

// ---------------- log-signature features -> bf16 rows (K-padded), LUT-parallel levy ----------------
struct SegTable { int st[50]; int en[50]; };

__global__ void feats_kernel(const float* __restrict__ xseq, bf16_t* __restrict__ feats,
                             SegTable segs, const unsigned short* __restrict__ lut,
                             int T, int d, int S, int L, int pairs, int rowlenP){
  __shared__ float pts[4][192];
  int bs = blockIdx.x;
  int b = bs / S, s = bs % S;
  int st = segs.st[s], en = segs.en[s];
  int nt = blockDim.x, tid = threadIdx.x;
  for (int l = 0; l < L; ++l){
    int t = st + l; if (t > en) t = en;
    for (int i = tid; i < d; i += nt) pts[l][i] = xseq[((size_t)b * T + t) * d + i];
  }
  __syncthreads();
  int rowlen = 2 * d + pairs;
  bf16_t* frow = feats + (size_t)bs * rowlenP;
  for (int i = tid; i < d; i += nt){
    frow[i] = f2bf(pts[0][i]);
    frow[d + i] = f2bf(pts[L - 1][i] - pts[0][i]);
  }
  for (int i = tid + rowlen; i < rowlenP; i += nt) frow[i] = 0;  // K pad
  int Lm2 = L - 2;
  bf16_t* lrow = frow + 2 * d;
  for (int p = tid; p < pairs; p += nt){
    int e = lut[p];
    int i = e >> 8, j = e & 255;
    float acc = 0.f;
    for (int l = 1; l <= Lm2; ++l){
      float ri = pts[l][i] - pts[0][i], rj = pts[l][j] - pts[0][j];
      float di = pts[l + 1][i] - pts[l][i], dj = pts[l + 1][j] - pts[l][j];
      acc += ri * dj - rj * di;
    }
    lrow[p] = f2bf(0.5f * acc);
  }
}

// ---------------- split-K MFMA bf16 NT GEMM, BK=64, XOR-swizzled LDS ----------------
// P[z] = A[M][K_z] * B[N][K_z]^T. Requires K % 64 == 0. M/N edges: clamp+predicate.
__global__ __launch_bounds__(256)
void gemm_mfma_nt_split(const bf16_t* __restrict__ A, const bf16_t* __restrict__ B,
                        float* __restrict__ P, int M, int N, int K){
  __shared__ bf16_t As[128 * 64];
  __shared__ bf16_t Bs[128 * 64];
  const int tid = threadIdx.x;
  const int lane = tid & 63, wv = tid >> 6;
  const int bm = blockIdx.x * 128, bn = blockIdx.y * 128;
  const int wr = (wv >> 1) * 64, wc = (wv & 1) * 64;
  const int m_l = lane & 15, q = lane >> 4;

  const int ksteps = K >> 6;
  const int Z = gridDim.z, z = blockIdx.z;
  const int per = (ksteps + Z - 1) / Z;
  const int ks0 = z * per;
  const int ks1 = (ks0 + per < ksteps) ? ks0 + per : ksteps;

  // staging: 16 chunks/matrix of 8 rows x 64 cols (1 KB); lane l covers
  // row_in = l>>3, slot s = l&7, global col-chunk = s ^ row_in (XOR swizzle).
  const int rlane = lane >> 3;
  const int slane = lane & 7;
  const int colc = (slane ^ rlane) * 8;
  const bf16_t* gA[4]; const bf16_t* gB[4];
  bf16_t* lA[4]; bf16_t* lB[4];
  #pragma unroll
  for (int it = 0; it < 4; ++it){
    int c = it * 4 + wv;
    int rowA = bm + c * 8 + rlane; if (rowA > M - 1) rowA = M - 1;
    int rowB = bn + c * 8 + rlane; if (rowB > N - 1) rowB = N - 1;
    gA[it] = A + (size_t)rowA * K + colc;
    gB[it] = B + (size_t)rowB * K + colc;
    lA[it] = &As[c * 512];
    lB[it] = &Bs[c * 512];
  }
  const int sxor = m_l & 7;  // row&7 for all fragment rows

  floatx4 acc[4][4] = {};
  for (int ks = ks0; ks < ks1; ++ks){
    int k0 = ks << 6;
    __syncthreads();
    #pragma unroll
    for (int it = 0; it < 4; ++it){
      gload_lds16(gA[it] + k0, lA[it]);
      gload_lds16(gB[it] + k0, lB[it]);
    }
    __syncthreads();
    #pragma unroll
    for (int half = 0; half < 2; ++half){
      const int scol = ((half * 4 + q) ^ sxor) * 8;
      short8 af[4], bfr[4];
      #pragma unroll
      for (int i = 0; i < 4; ++i){
        af[i]  = *reinterpret_cast<const short8*>(&As[(wr + i * 16 + m_l) * 64 + scol]);
        bfr[i] = *reinterpret_cast<const short8*>(&Bs[(wc + i * 16 + m_l) * 64 + scol]);
      }
      #pragma unroll
      for (int mi = 0; mi < 4; ++mi)
        #pragma unroll
        for (int ni = 0; ni < 4; ++ni)
          acc[mi][ni] = __builtin_amdgcn_mfma_f32_16x16x32_bf16(af[mi], bfr[ni], acc[mi][ni], 0, 0, 0);
    }
  }

  float* Pz = P + (size_t)z * M * N;
  #pragma unroll
  for (int mi = 0; mi < 4; ++mi){
    int row0 = bm + wr + mi * 16 + q * 4;
    #pragma unroll
    for (int r = 0; r < 4; ++r){
      int row = row0 + r;
      if (row < M){
        #pragma unroll
        for (int ni = 0; ni < 4; ++ni){
          int col = bn + wc + ni * 16 + m_l;
          if (col < N) Pz[(size_t)row * N + col] = acc[mi][ni][r];
        }
      }
    }
  }
}

// ---------------- reduce split partials + bias (GCN2 path) ----------------
__global__ void reduce_split_bias(const float* __restrict__ P, const float* __restrict__ bias,
                                  float* __restrict__ out, int MN, int N, int Z){
  int i4 = (blockIdx.x * blockDim.x + threadIdx.x) * 4;
  if (i4 >= MN) return;
  const float4 bv = *reinterpret_cast<const float4*>(bias + (i4 % N));
  float4 s = bv;
  for (int z = 0; z < Z; ++z){
    const float4 p = *reinterpret_cast<const float4*>(P + (size_t)z * MN + i4);
    s.x += p.x; s.y += p.y; s.z += p.z; s.w += p.w;
  }
  *reinterpret_cast<float4*>(out + i4) = s;
}

// ---------------- persistent per-sequence LSTM: register f16 weights, fused split-K reduce ----------------
template <int H2C, int BLK, int Z>
__global__ __launch_bounds__(BLK)
void lstm_kernel(const float* __restrict__ P, const float* __restrict__ bias,
                 const half2_t* __restrict__ Wp, float* __restrict__ out,
                 int S, int MN){
  constexpr int H = 2 * H2C;
  constexpr int H4 = 4 * H;
  __shared__ _Float16 __attribute__((aligned(16))) hsh[H];
  __shared__ float gv[H4];
  const int b = blockIdx.x, t = threadIdx.x;
  half2_t w[H2C];
  const half2_t* wp = Wp + t;
  #pragma unroll
  for (int j2 = 0; j2 < H2C; ++j2) w[j2] = wp[(size_t)j2 * H4];
  float cc = 0.f;
  if (t < H) hsh[t] = (_Float16)0.f;
  const float bval = bias[t];
  __syncthreads();
  const half2_t* hp = reinterpret_cast<const half2_t*>(hsh);
  for (int s = 0; s < S; ++s){
    size_t rowoff = ((size_t)b * S + s) * H4 + t;
    float pv[Z];
    #pragma unroll
    for (int z = 0; z < Z; ++z) pv[z] = P[(size_t)z * MN + rowoff];
    float a0 = bval, a1 = 0.f, a2 = 0.f, a3 = 0.f;
    #pragma unroll
    for (int z = 0; z < Z; ++z) a0 += pv[z];
    #pragma unroll
    for (int j2 = 0; j2 < H2C; j2 += 4){
      a0 = dot2(w[j2],     hp[j2],     a0);
      a1 = dot2(w[j2 + 1], hp[j2 + 1], a1);
      a2 = dot2(w[j2 + 2], hp[j2 + 2], a2);
      a3 = dot2(w[j2 + 3], hp[j2 + 3], a3);
    }
    gv[t] = (a0 + a1) + (a2 + a3);
    __syncthreads();
    if (t < H){
      float ig = sigf(gv[t]);
      float fg = sigf(gv[H + t]);
      float gg = tanhf(gv[2 * H + t]);
      float og = sigf(gv[3 * H + t]);
      cc = fg * cc + ig * gg;
      float hh = og * tanhf(cc);
      hsh[t] = (_Float16)hh;
      out[((size_t)b * S + s) * H + t] = hh;
    }
    __syncthreads();
  }
}

// ---------------- bnseg (from sums) apply + transpose to gcn2 input layout ----------------
__global__ void bnseg_to_g2in_kernel(const float* __restrict__ lout, const float* __restrict__ sum,
                                     const float* __restrict__ sumsq, const float* __restrict__ g,
                                     const float* __restrict__ bb, float* __restrict__ g2in,
                                     int B, int S, int H, int cnt){
  int idx = blockIdx.x * blockDim.x + threadIdx.x;
  int total = B * S * H;
  if (idx >= total) return;
  int hh = idx % H;
  int s = (idx / H) % S;
  int b = idx / (H * S);
  float mean = sum[s] / cnt;
  float rstd = rsqrtf(sumsq[s] / cnt - mean * mean + 1e-5f);
  float val = (lout[idx] - mean) * rstd * g[s] + bb[s];
  int nm = b / 25, v = b % 25;
  g2in[((size_t)((nm * H + hh) * S) + s) * 25 + v] = val;
}

// ---------------- support2 -> bf16 A2mat[(nm*S+s)*25+v][k*96+c], row stride 1280 ----------------
__global__ void support2_kernel(const float* __restrict__ A, const float* __restrict__ g2in,
                                bf16_t* __restrict__ A2mat, int NM, int C1, int S){
  int idx = blockIdx.x * blockDim.x + threadIdx.x;
  int total = NM * C1 * S * 325;
  if (idx >= total) return;
  int w = idx % 325;
  int s = (idx / 325) % S;
  int c = (idx / (325 * S)) % C1;
  int nm = idx / (325 * S * C1);
  const float* row = g2in + ((size_t)((nm * C1 + c) * S) + s) * 25;
  const float* ar = A + w * 25;
  float acc = 0.f;
  #pragma unroll
  for (int u = 0; u < 25; ++u) acc += ar[u] * row[u];
  int k = w / 25, v = w % 25;
  A2mat[((size_t)((nm * S + s) * 25 + v)) * 1280 + k * C1 + c] = f2bf(acc);
}

// ---------------- bnseg2 (from sums) + global pool ----------------
__global__ void pool_kernel(const float* __restrict__ lout2, const float* __restrict__ sum,
                            const float* __restrict__ sumsq, const float* __restrict__ g,
                            const float* __restrict__ bb, float* __restrict__ pooled,
                            int S, int H, int scnt){
  int n = blockIdx.x / H;
  int o = blockIdx.x % H;
  float acc = 0.f;
  int cnt = 2 * 25 * S;
  for (int i = threadIdx.x; i < cnt; i += 64){
    int m = i / (25 * S);
    int r = i % (25 * S);
    int v = r / S;
    int s = r % S;
    int b = (n * 2 + m) * 25 + v;
    float val = lout2[((size_t)b * S + s) * H + o];
    float mean = sum[s] / scnt;
    float rstd = rsqrtf(sumsq[s] / scnt - mean * mean + 1e-5f);
    val = (val - mean) * rstd * g[s] + bb[s];
    acc += val;
  }
  for (int off = 32; off; off >>= 1) acc += __shfl_down(acc, off);
  if (threadIdx.x == 0) pooled[n * H + o] = acc / cnt;
}

// ---------------- final FC ----------------
__global__ void fc_kernel(const float* __restrict__ pooled, const float* __restrict__ fcW,
                          const float* __restrict__ fcb, float* __restrict__ outp){
  int idx = blockIdx.x * blockDim.x + threadIdx.x;
  if (idx >= 120) return;
  int n = idx / 60, cls = idx % 60;
  float acc = fcb[cls];
  for (int o = 0; o < 192; ++o) acc += pooled[n * 192 + o] * fcW[cls * 192 + o];
  outp[idx] = acc;
}

// ---------------- host: replicate np.linspace + python round (ties-to-even) ----------------
static void make_segs(int T, int S, SegTable& tab, int& L){
  double step = (double)(T - 1) / (double)S;
  long long tv[51];
  for (int i = 0; i <= S; ++i){
    double v = 1.0 + step * (double)i;
    tv[i] = llrint(v);
  }
  L = 0;
  for (int s = 0; s < S; ++s){
    tab.st[s] = (int)tv[s] - 1;
    tab.en[s] = (int)tv[s + 1] - 1;
    int len = tab.en[s] - tab.st[s] + 1;
    if (len > L) L = len;
  }
  for (int s = S; s < 50; ++s){ tab.st[s] = 0; tab.en[s] = 0; }
  if (L > 4) L = 4;
}

extern "C" void kernel_launch(void* const* d_in, const int* in_sizes, int n_in,
                              void* d_out, int out_size, void* d_ws, size_t ws_size,
                              hipStream_t stream){
  const float* x         = (const float*)d_in[0];
  const float* data_bn_g = (const float*)d_in[2];
  const float* data_bn_b = (const float*)d_in[3];
  const float* A_powers1 = (const float*)d_in[4];
  const float* A_res1    = (const float*)d_in[5];
  const float* W1        = (const float*)d_in[6];
  const float* b1        = (const float*)d_in[7];
  const float* bn1_g     = (const float*)d_in[8];
  const float* bn1_b     = (const float*)d_in[9];
  const float* Wih1      = (const float*)d_in[10];
  const float* Whh1      = (const float*)d_in[11];
  const float* bih1      = (const float*)d_in[12];
  const float* bhh1      = (const float*)d_in[13];
  const float* bnseg1_g  = (const float*)d_in[14];
  const float* bnseg1_b  = (const float*)d_in[15];
  const float* A_powers2 = (const float*)d_in[16];
  const float* A_res2    = (const float*)d_in[17];
  const float* W2        = (const float*)d_in[18];
  const float* b2        = (const float*)d_in[19];
  const float* bn2_g     = (const float*)d_in[20];
  const float* bn2_b     = (const float*)d_in[21];
  const float* Wih2      = (const float*)d_in[22];
  const float* Whh2      = (const float*)d_in[23];
  const float* bih2      = (const float*)d_in[24];
  const float* bhh2      = (const float*)d_in[25];
  const float* bnseg2_g  = (const float*)d_in[26];
  const float* bnseg2_b  = (const float*)d_in[27];
  const float* fcW       = (const float*)d_in[28];
  const float* fcb       = (const float*)d_in[29];
  float* out = (float*)d_out;

  const int N = 2, C = 3, T = 100, V = 25, M = 2, NM = 4;
  const int K = 13, C1 = 96, C2 = 192;
  const int S1 = 50, S2 = 30;
  const int B = 100;
  const int IN1 = 4752, IN2 = 18720;
  const int IN1P = 4800, IN2P = 18752;  // K padded to %64
  const int P1 = 4560, P2 = 18336;
  const int KG2 = 1248, KG2P = 1280;
  const int Z1 = 5, Z2 = 6, ZG = 4;

  size_t off = 0;
  char* base = (char*)d_ws;
  auto alloc = [&](size_t nbytes) -> void* {
    off = (off + 255) & ~(size_t)255;
    void* p = base + off;
    off += nbytes;
    return p;
  };
  float* A1full = (float*)alloc(325 * 25 * 4);
  float* A2full = (float*)alloc(325 * 25 * 4);
  float* h1     = (float*)alloc((size_t)NM * C * T * V * 4);
  float* sup1   = (float*)alloc((size_t)NM * C * T * 325 * 4);
  float* y1mat  = (float*)alloc((size_t)NM * T * V * C1 * 4);
  float* stats  = (float*)alloc(736 * 4);
  float* st1a = stats, *st1b = stats + 96;
  float* sg1a = stats + 192, *sg1b = stats + 242;
  float* st2a = stats + 292, *st2b = stats + 484;
  float* sg2a = stats + 676, *sg2b = stats + 706;
  float* xseq1  = (float*)alloc((size_t)B * T * C1 * 4);
  float* l1out  = (float*)alloc((size_t)B * S1 * C1 * 4);
  float* g2in   = (float*)alloc((size_t)NM * C1 * S1 * V * 4);
  bf16_t* A2mat = (bf16_t*)alloc((size_t)NM * S1 * V * KG2P * 2);
  float* y2mat  = (float*)alloc((size_t)NM * S1 * V * C2 * 4);
  float* xseq2  = (float*)alloc((size_t)B * S1 * C2 * 4);
  float* l2out  = (float*)alloc((size_t)B * S2 * C2 * 4);
  float* pooled = (float*)alloc(2 * C2 * 4);
  float* bias1  = (float*)alloc(4 * C1 * 4);
  float* bias2  = (float*)alloc(4 * C2 * 4);
  half2_t* Wp1  = (half2_t*)alloc((size_t)(C1 / 2) * 4 * C1 * 4);
  half2_t* Wp2  = (half2_t*)alloc((size_t)(C2 / 2) * 4 * C2 * 4);
  bf16_t* Wih1b = (bf16_t*)alloc((size_t)4 * C1 * IN1P * 2);
  bf16_t* Wih2b = (bf16_t*)alloc((size_t)4 * C2 * IN2P * 2);
  bf16_t* W2b   = (bf16_t*)alloc((size_t)C2 * KG2P * 2);
  unsigned short* lut1 = (unsigned short*)alloc((size_t)P1 * 2);
  unsigned short* lut2 = (unsigned short*)alloc((size_t)P2 * 2);
  size_t pmax = (size_t)Z2 * 3000 * 768;
  {
    size_t p1s = (size_t)Z1 * 5000 * 384; if (p1s > pmax) pmax = p1s;
    size_t pgs = (size_t)ZG * 5000 * 192; if (pgs > pmax) pmax = pgs;
  }
  float* Pbuf = (float*)alloc(pmax * 4);
  bf16_t* feats = (bf16_t*)alloc((size_t)B * S2 * IN2P * 2);
  (void)ws_size; (void)in_sizes; (void)n_in; (void)out_size;

  // one prep dispatch: adds, whh packs, LUTs, stat zeros, A2mat K-pad
  prep_misc<<<625, 256, 0, stream>>>(A_powers1, A_res1, A1full, A_powers2, A_res2, A2full,
                                     bih1, bhh1, bias1, bih2, bhh2, bias2,
                                     Whh1, Wp1, Whh2, Wp2, lut1, lut2, stats, A2mat);
  f2bf_pad8<<<(4 * C1 * (IN1P / 8) + 255) / 256, 256, 0, stream>>>(Wih1, Wih1b, 4 * C1, IN1, IN1P);
  f2bf_pad8<<<(4 * C2 * (IN2P / 8) + 255) / 256, 256, 0, stream>>>(Wih2, Wih2b, 4 * C2, IN2, IN2P);
  f2bf_pad8<<<(C2 * (KG2P / 8) + 255) / 256, 256, 0, stream>>>(W2, W2b, C2, KG2, KG2P);

  // stage 0: data BN
  data_bn_kernel<<<M * V * C, 64, 0, stream>>>(x, data_bn_g, data_bn_b, h1, N, C, T, V, M);

  // stage 1: GCN1
  int tot_sup1 = NM * C * T * 325;
  support1_kernel<<<(tot_sup1 + 255) / 256, 256, 0, stream>>>(A1full, h1, sup1, tot_sup1);
  int tot_y1 = NM * T * 25 * C1;
  gcn1_out_kernel<<<(tot_y1 + 255) / 256, 256, 0, stream>>>(sup1, W1, b1, y1mat, NM, T);
  colstats_atomic<<<256, C1, 0, stream>>>(y1mat, NM * T * 25, st1a, st1b);
  bn_relu_seq_kernel<<<(tot_y1 + 255) / 256, 256, 0, stream>>>(y1mat, st1a, st1b, bn1_g, bn1_b,
                                                               xseq1, NM, T, C1, NM * T * 25);

  // stage 1: logsig-rnn
  SegTable seg1, seg2; int L1, L2;
  make_segs(T, S1, seg1, L1);
  make_segs(S1, S2, seg2, L2);

  feats_kernel<<<B * S1, 256, 0, stream>>>(xseq1, feats, seg1, lut1, T, C1, S1, L1, P1, IN1P);
  {
    int Mm = B * S1, Nn = 4 * C1;
    dim3 g((Mm + 127) / 128, (Nn + 127) / 128, Z1);
    gemm_mfma_nt_split<<<g, 256, 0, stream>>>(feats, Wih1b, Pbuf, Mm, Nn, IN1P);
    lstm_kernel<48, 384, Z1><<<B, 384, 0, stream>>>(Pbuf, bias1, Wp1, l1out, S1, Mm * Nn);
  }
  segstats_atomic<<<256, C1, 0, stream>>>(l1out, B * S1, S1, sg1a, sg1b);
  int tot_bn1 = B * S1 * C1;
  bnseg_to_g2in_kernel<<<(tot_bn1 + 255) / 256, 256, 0, stream>>>(l1out, sg1a, sg1b, bnseg1_g,
                                                                  bnseg1_b, g2in, B, S1, C1, B * C1);

  // stage 2: GCN2 (MFMA, split-K)
  int tot_sup2 = NM * C1 * S1 * 325;
  support2_kernel<<<(tot_sup2 + 255) / 256, 256, 0, stream>>>(A2full, g2in, A2mat, NM, C1, S1);
  {
    int Mm = NM * S1 * 25, Nn = C2;
    dim3 g((Mm + 127) / 128, (Nn + 127) / 128, ZG);
    gemm_mfma_nt_split<<<g, 256, 0, stream>>>(A2mat, W2b, Pbuf, Mm, Nn, KG2P);
    int MN = Mm * Nn;
    reduce_split_bias<<<(MN / 4 + 255) / 256, 256, 0, stream>>>(Pbuf, b2, y2mat, MN, Nn, ZG);
  }
  colstats_atomic<<<256, C2, 0, stream>>>(y2mat, NM * S1 * 25, st2a, st2b);
  int tot_y2 = NM * S1 * 25 * C2;
  bn_relu_seq_kernel<<<(tot_y2 + 255) / 256, 256, 0, stream>>>(y2mat, st2a, st2b, bn2_g, bn2_b,
                                                               xseq2, NM, S1, C2, NM * S1 * 25);

  // stage 2: logsig-rnn
  feats_kernel<<<B * S2, 256, 0, stream>>>(xseq2, feats, seg2, lut2, S1, C2, S2, L2, P2, IN2P);
  {
    int Mm = B * S2, Nn = 4 * C2;
    dim3 g((Mm + 127) / 128, (Nn + 127) / 128, Z2);
    gemm_mfma_nt_split<<<g, 256, 0, stream>>>(feats, Wih2b, Pbuf, Mm, Nn, IN2P);
    lstm_kernel<96, 768, Z2><<<B, 768, 0, stream>>>(Pbuf, bias2, Wp2, l2out, S2, Mm * Nn);
  }
  segstats_atomic<<<256, C2, 0, stream>>>(l2out, B * S2, S2, sg2a, sg2b);

  // pool + fc
  pool_kernel<<<2 * C2, 64, 0, stream>>>(l2out, sg2a, sg2b, bnseg2_g, bnseg2_b, pooled, S2, C2, B * C2);
  fc_kernel<<<1, 128, 0, stream>>>(pooled, fcW, fcb, out);
}

// Round 6
// 706.669 us; speedup vs baseline: 4.2281x; 1.0814x over previous
//
#include <hip/hip_runtime.h>
#include <cmath>
#include <cstdint>
#include <cstddef>

typedef unsigned short bf16_t;
typedef __attribute__((ext_vector_type(8))) short short8;
typedef __attribute__((ext_vector_type(4))) float floatx4;
typedef __attribute__((ext_vector_type(2))) _Float16 half2_t;

__device__ __forceinline__ float bf2f(bf16_t b){
  unsigned int u = ((unsigned int)b) << 16;
  return __uint_as_float(u);
}
__device__ __forceinline__ bf16_t f2bf(float f){
  unsigned int u = __float_as_uint(f);
  unsigned int r = (u + 0x7fffu + ((u >> 16) & 1u)) >> 16;  // RNE
  return (bf16_t)r;
}
__device__ __forceinline__ unsigned int f2bf2(float a, float b){
  return (unsigned int)f2bf(a) | ((unsigned int)f2bf(b) << 16);
}
__device__ __forceinline__ float sigf(float x){ return 1.0f / (1.0f + expf(-x)); }

__device__ __forceinline__ float dot2(half2_t a, half2_t b, float c){
#if __has_builtin(__builtin_amdgcn_fdot2)
  return __builtin_amdgcn_fdot2(a, b, c, false);
#else
  return c + (float)a.x * (float)b.x + (float)a.y * (float)b.y;
#endif
}

__device__ __forceinline__ void gload_lds16(const bf16_t* g, bf16_t* lds){
  __builtin_amdgcn_global_load_lds(
      (const __attribute__((address_space(1))) unsigned int*)g,
      (__attribute__((address_space(3))) unsigned int*)lds, 16, 0, 0);
}

// ---------------- mega prep kernel: adds, whh pack, LUTs, stat zero, A2mat K-pad ----------------
__global__ void prep_misc(const float* __restrict__ a1, const float* __restrict__ r1, float* __restrict__ o1,
                          const float* __restrict__ a2, const float* __restrict__ r2, float* __restrict__ o2,
                          const float* __restrict__ bi1, const float* __restrict__ bh1, float* __restrict__ ob1,
                          const float* __restrict__ bi2, const float* __restrict__ bh2, float* __restrict__ ob2,
                          const float* __restrict__ Whh1, half2_t* __restrict__ Wp1,
                          const float* __restrict__ Whh2, half2_t* __restrict__ Wp2,
                          unsigned short* __restrict__ lut1, unsigned short* __restrict__ lut2,
                          float* __restrict__ stats, bf16_t* __restrict__ A2mat){
  int i = blockIdx.x * blockDim.x + threadIdx.x;
  if (i < 8125){ o1[i] = a1[i] + r1[i]; o2[i] = a2[i] + r2[i]; }
  if (i < 384) ob1[i] = bi1[i] + bh1[i];
  if (i < 768) ob2[i] = bi2[i] + bh2[i];
  if (i < 736) stats[i] = 0.f;
  if (i < 18432){                       // pack Whh1 (H=96): Wp[j2*384+t]
    int t = i % 384, j2 = i / 384;
    half2_t w; w.x = (_Float16)Whh1[(size_t)t * 96 + 2 * j2];
    w.y = (_Float16)Whh1[(size_t)t * 96 + 2 * j2 + 1];
    Wp1[i] = w;
  }
  if (i < 73728){                       // pack Whh2 (H=192)
    int t = i % 768, j2 = i / 768;
    half2_t w; w.x = (_Float16)Whh2[(size_t)t * 192 + 2 * j2];
    w.y = (_Float16)Whh2[(size_t)t * 192 + 2 * j2 + 1];
    Wp2[i] = w;
  }
  // levy pair LUTs: flat p -> (i<<8)|j
  if (i < 4560){
    int d = 96, p = i;
    int r = (int)(((2.0 * d - 1.0) - sqrt((2.0 * d - 1.0) * (2.0 * d - 1.0) - 8.0 * (double)p)) * 0.5);
    if (r < 0) r = 0;
    while (r + 1 <= d - 2 && (r + 1) * (d - 1) - ((r + 1) * r) / 2 <= p) ++r;
    while (r > 0 && r * (d - 1) - (r * (r - 1)) / 2 > p) --r;
    int jj = p - (r * (d - 1) - (r * (r - 1)) / 2);
    lut1[p] = (unsigned short)((r << 8) | (r + 1 + jj));
  }
  if (i < 18336){
    int d = 192, p = i;
    int r = (int)(((2.0 * d - 1.0) - sqrt((2.0 * d - 1.0) * (2.0 * d - 1.0) - 8.0 * (double)p)) * 0.5);
    if (r < 0) r = 0;
    while (r + 1 <= d - 2 && (r + 1) * (d - 1) - ((r + 1) * r) / 2 <= p) ++r;
    while (r > 0 && r * (d - 1) - (r * (r - 1)) / 2 > p) --r;
    int jj = p - (r * (d - 1) - (r * (r - 1)) / 2);
    lut2[p] = (unsigned short)((r << 8) | (r + 1 + jj));
  }
  if (i < 160000){                      // A2mat K-pad cols [1248,1280), 5000 rows
    int row = i >> 5, col = 1248 + (i & 31);
    A2mat[(size_t)row * 1280 + col] = 0;
  }
}

// ---------------- three fp32->bf16 pad conversions in ONE dispatch ----------------
__device__ __forceinline__ void f2bf_seg(const float* in, bf16_t* out, int Kin, int Kout, int li){
  int ko8 = Kout >> 3;
  int r = li / ko8, k8 = (li % ko8) << 3;
  uint4 u;
  if (k8 + 8 <= Kin){
    const float4* p = reinterpret_cast<const float4*>(in + (size_t)r * Kin + k8);
    float4 x0 = p[0], x1 = p[1];
    u.x = f2bf2(x0.x, x0.y); u.y = f2bf2(x0.z, x0.w);
    u.z = f2bf2(x1.x, x1.y); u.w = f2bf2(x1.z, x1.w);
  } else {
    u.x = u.y = u.z = u.w = 0u;
  }
  *reinterpret_cast<uint4*>(out + (size_t)r * Kout + k8) = u;
}

__global__ void f2bf_pad8_3(const float* __restrict__ in1, bf16_t* __restrict__ out1, int Kin1, int Kout1, int c1,
                            const float* __restrict__ in2, bf16_t* __restrict__ out2, int Kin2, int Kout2, int c2,
                            const float* __restrict__ in3, bf16_t* __restrict__ out3, int Kin3, int Kout3, int c3){
  int idx = blockIdx.x * blockDim.x + threadIdx.x;
  if (idx < c1){ f2bf_seg(in1, out1, Kin1, Kout1, idx); return; }
  idx -= c1;
  if (idx < c2){ f2bf_seg(in2, out2, Kin2, Kout2, idx); return; }
  idx -= c2;
  if (idx < c3) f2bf_seg(in3, out3, Kin3, Kout3, idx);
}

// ---------------- data batchnorm: x(N,C,T,V,M) -> h1[(nm*C+c)*T+t][V] ----------------
__global__ void data_bn_kernel(const float* __restrict__ x, const float* __restrict__ g,
                               const float* __restrict__ bb, float* __restrict__ h1,
                               int N, int C, int T, int V, int M){
  int ch = blockIdx.x;             // (m*V + v)*C + c
  int m = ch / (V * C);
  int v = (ch / C) % V;
  int c = ch % C;
  int tid = threadIdx.x;
  int cnt = N * T;
  float s = 0.f, s2 = 0.f;
  for (int i = tid; i < cnt; i += 64){
    int n = i / T, t = i % T;
    float val = x[(((size_t)(n * C + c) * T + t) * V + v) * M + m];
    s += val; s2 += val * val;
  }
  for (int off = 32; off; off >>= 1){ s += __shfl_down(s, off); s2 += __shfl_down(s2, off); }
  s = __shfl(s, 0); s2 = __shfl(s2, 0);
  float mean = s / cnt;
  float rstd = rsqrtf(s2 / cnt - mean * mean + 1e-5f);
  float gg = g[ch], bo = bb[ch];
  for (int i = tid; i < cnt; i += 64){
    int n = i / T, t = i % T;
    float val = x[(((size_t)(n * C + c) * T + t) * V + v) * M + m];
    float y = (val - mean) * rstd * gg + bo;
    h1[((size_t)((n * M + m) * C + c) * T + t) * V + v] = y;
  }
}

// ---------------- support1: sup[row][w] = sum_u A[w][u]*hin[row][u] ----------------
__global__ void support1_kernel(const float* __restrict__ A, const float* __restrict__ hin,
                                float* __restrict__ sup, int total){
  int idx = blockIdx.x * blockDim.x + threadIdx.x;
  if (idx >= total) return;
  int w = idx % 325;
  int rest = idx / 325;
  const float* row = hin + (size_t)rest * 25;
  const float* ar = A + w * 25;
  float acc = 0.f;
  #pragma unroll
  for (int u = 0; u < 25; ++u) acc += ar[u] * row[u];
  sup[idx] = acc;
}

// ---------------- gcn1 output: y1[((nm*T+t)*25+v)*96+o] ----------------
__global__ void gcn1_out_kernel(const float* __restrict__ sup, const float* __restrict__ W1,
                                const float* __restrict__ b1, float* __restrict__ y1, int NM, int T){
  int idx = blockIdx.x * blockDim.x + threadIdx.x;
  int total = NM * T * 25 * 96;
  if (idx >= total) return;
  int o = idx % 96;
  int v = (idx / 96) % 25;
  int t = (idx / (96 * 25)) % T;
  int nm = idx / (96 * 25 * T);
  float acc = b1[o];
  #pragma unroll
  for (int k = 0; k < 13; ++k)
    #pragma unroll
    for (int c = 0; c < 3; ++c)
      acc += W1[o * 39 + k * 3 + c] * sup[(size_t)((nm * 3 + c) * T + t) * 325 + k * 25 + v];
  y1[idx] = acc;
}

// ---------------- coalesced column-stat accumulate (blockDim == Cc) ----------------
__global__ void colstats_atomic(const float* __restrict__ mat, int R,
                                float* __restrict__ sum, float* __restrict__ sumsq){
  int col = threadIdx.x;
  int Cc = blockDim.x;
  float s = 0.f, s2 = 0.f;
  for (int r = blockIdx.x; r < R; r += gridDim.x){
    float v = mat[(size_t)r * Cc + col];
    s += v; s2 += v * v;
  }
  atomicAdd(&sum[col], s);
  atomicAdd(&sumsq[col], s2);
}

// ---------------- coalesced per-segment stat accumulate (blockDim == H) ----------------
__global__ void segstats_atomic(const float* __restrict__ lout, int R2, int S,
                                float* __restrict__ sum, float* __restrict__ sumsq){
  int t = threadIdx.x;
  int H = blockDim.x;
  int nw = H >> 6;
  __shared__ float ra[4], rb[4];
  int lane = t & 63, wid = t >> 6;
  for (int r = blockIdx.x; r < R2; r += gridDim.x){
    int s = r % S;
    float v = lout[(size_t)r * H + t];
    float a = v, b2 = v * v;
    for (int off = 32; off; off >>= 1){ a += __shfl_down(a, off); b2 += __shfl_down(b2, off); }
    if (lane == 0){ ra[wid] = a; rb[wid] = b2; }
    __syncthreads();
    if (t == 0){
      float sa = 0.f, sb = 0.f;
      for (int w = 0; w < nw; ++w){ sa += ra[w]; sb += rb[w]; }
      atomicAdd(&sum[s], sa);
      atomicAdd(&sumsq[s], sb);
    }
    __syncthreads();
  }
}

// ---------------- bn (from sums) + relu + transpose to sequence layout ----------------
__global__ void bn_relu_seq_kernel(const float* __restrict__ ymat, const float* __restrict__ sum,
                                   const float* __restrict__ sumsq, const float* __restrict__ g,
                                   const float* __restrict__ bb, float* __restrict__ xseq,
                                   int NM, int T, int H, int R){
  int idx = blockIdx.x * blockDim.x + threadIdx.x;
  int total = NM * T * 25 * H;
  if (idx >= total) return;
  int o = idx % H;
  int v = (idx / H) % 25;
  int t = (idx / (H * 25)) % T;
  int nm = idx / (H * 25 * T);
  float mean = sum[o] / R;
  float rstd = rsqrtf(sumsq[o] / R - mean * mean + 1e-5f);
  float val = (ymat[idx] - mean) * rstd * g[o] + bb[o];
  val = fmaxf(val, 0.f);
  int b = nm * 25 + v;
  xseq[((size_t)b * T + t) * H + o] = val;
}

// ---------------- log-signature features -> bf16 rows, packed 32-bit stores ----------------
struct SegTable { int st[50]; int en[50]; };

__global__ void feats_kernel(const float* __restrict__ xseq, bf16_t* __restrict__ feats,
                             SegTable segs, const unsigned int* __restrict__ lut32,
                             int T, int d, int S, int L, int pairs, int rowlenP){
  __shared__ float pts[4][192];
  int bs = blockIdx.x;
  int b = bs / S, s = bs % S;
  int st = segs.st[s], en = segs.en[s];
  int nt = blockDim.x, tid = threadIdx.x;
  for (int l = 0; l < L; ++l){
    int t = st + l; if (t > en) t = en;
    for (int i = tid; i < d; i += nt) pts[l][i] = xseq[((size_t)b * T + t) * d + i];
  }
  __syncthreads();
  unsigned int* frow32 = reinterpret_cast<unsigned int*>(feats + (size_t)bs * rowlenP);
  int d2 = d >> 1;
  for (int i2 = tid; i2 < d2; i2 += nt){
    int i = 2 * i2;
    frow32[i2]      = f2bf2(pts[0][i], pts[0][i + 1]);
    frow32[d2 + i2] = f2bf2(pts[L - 1][i] - pts[0][i], pts[L - 1][i + 1] - pts[0][i + 1]);
  }
  int rowlen2 = (2 * d + pairs) >> 1, rowlenP2 = rowlenP >> 1;
  for (int i = tid + rowlen2; i < rowlenP2; i += nt) frow32[i] = 0;  // K pad
  int Lm2 = L - 2;
  unsigned int* lrow32 = frow32 + d;
  int pairs2 = pairs >> 1;
  for (int p2 = tid; p2 < pairs2; p2 += nt){
    unsigned int ee = lut32[p2];
    int i0 = (ee >> 8) & 255, j0 = ee & 255;
    int i1 = ee >> 24, j1 = (ee >> 16) & 255;
    float acc0 = 0.f, acc1 = 0.f;
    for (int l = 1; l <= Lm2; ++l){
      float p0i = pts[0][i0], p0j = pts[0][j0], p0i1 = pts[0][i1], p0j1 = pts[0][j1];
      float ri = pts[l][i0] - p0i, rj = pts[l][j0] - p0j;
      float di = pts[l + 1][i0] - pts[l][i0], dj = pts[l + 1][j0] - pts[l][j0];
      acc0 += ri * dj - rj * di;
      float ri1 = pts[l][i1] - p0i1, rj1 = pts[l][j1] - p0j1;
      float di1 = pts[l + 1][i1] - pts[l][i1], dj1 = pts[l + 1][j1] - pts[l][j1];
      acc1 += ri1 * dj1 - rj1 * di1;
    }
    lrow32[p2] = f2bf2(0.5f * acc0, 0.5f * acc1);
  }
}

// ---------------- split-K MFMA bf16 NT GEMM, BK=64, XOR-swizzled LDS ----------------
__global__ __launch_bounds__(256)
void gemm_mfma_nt_split(const bf16_t* __restrict__ A, const bf16_t* __restrict__ B,
                        float* __restrict__ P, int M, int N, int K){
  __shared__ bf16_t As[128 * 64];
  __shared__ bf16_t Bs[128 * 64];
  const int tid = threadIdx.x;
  const int lane = tid & 63, wv = tid >> 6;
  const int bm = blockIdx.x * 128, bn = blockIdx.y * 128;
  const int wr = (wv >> 1) * 64, wc = (wv & 1) * 64;
  const int m_l = lane & 15, q = lane >> 4;

  const int ksteps = K >> 6;
  const int Z = gridDim.z, z = blockIdx.z;
  const int per = (ksteps + Z - 1) / Z;
  const int ks0 = z * per;
  const int ks1 = (ks0 + per < ksteps) ? ks0 + per : ksteps;

  const int rlane = lane >> 3;
  const int slane = lane & 7;
  const int colc = (slane ^ rlane) * 8;
  const bf16_t* gA[4]; const bf16_t* gB[4];
  bf16_t* lA[4]; bf16_t* lB[4];
  #pragma unroll
  for (int it = 0; it < 4; ++it){
    int c = it * 4 + wv;
    int rowA = bm + c * 8 + rlane; if (rowA > M - 1) rowA = M - 1;
    int rowB = bn + c * 8 + rlane; if (rowB > N - 1) rowB = N - 1;
    gA[it] = A + (size_t)rowA * K + colc;
    gB[it] = B + (size_t)rowB * K + colc;
    lA[it] = &As[c * 512];
    lB[it] = &Bs[c * 512];
  }
  const int sxor = m_l & 7;

  floatx4 acc[4][4] = {};
  for (int ks = ks0; ks < ks1; ++ks){
    int k0 = ks << 6;
    __syncthreads();
    #pragma unroll
    for (int it = 0; it < 4; ++it){
      gload_lds16(gA[it] + k0, lA[it]);
      gload_lds16(gB[it] + k0, lB[it]);
    }
    __syncthreads();
    #pragma unroll
    for (int half = 0; half < 2; ++half){
      const int scol = ((half * 4 + q) ^ sxor) * 8;
      short8 af[4], bfr[4];
      #pragma unroll
      for (int i = 0; i < 4; ++i){
        af[i]  = *reinterpret_cast<const short8*>(&As[(wr + i * 16 + m_l) * 64 + scol]);
        bfr[i] = *reinterpret_cast<const short8*>(&Bs[(wc + i * 16 + m_l) * 64 + scol]);
      }
      #pragma unroll
      for (int mi = 0; mi < 4; ++mi)
        #pragma unroll
        for (int ni = 0; ni < 4; ++ni)
          acc[mi][ni] = __builtin_amdgcn_mfma_f32_16x16x32_bf16(af[mi], bfr[ni], acc[mi][ni], 0, 0, 0);
    }
  }

  float* Pz = P + (size_t)z * M * N;
  #pragma unroll
  for (int mi = 0; mi < 4; ++mi){
    int row0 = bm + wr + mi * 16 + q * 4;
    #pragma unroll
    for (int r = 0; r < 4; ++r){
      int row = row0 + r;
      if (row < M){
        #pragma unroll
        for (int ni = 0; ni < 4; ++ni){
          int col = bn + wc + ni * 16 + m_l;
          if (col < N) Pz[(size_t)row * N + col] = acc[mi][ni][r];
        }
      }
    }
  }
}

// ---------------- reduce split partials + bias (GCN2 path) ----------------
__global__ void reduce_split_bias(const float* __restrict__ P, const float* __restrict__ bias,
                                  float* __restrict__ out, int MN, int N, int Z){
  int i4 = (blockIdx.x * blockDim.x + threadIdx.x) * 4;
  if (i4 >= MN) return;
  const float4 bv = *reinterpret_cast<const float4*>(bias + (i4 % N));
  float4 s = bv;
  for (int z = 0; z < Z; ++z){
    const float4 p = *reinterpret_cast<const float4*>(P + (size_t)z * MN + i4);
    s.x += p.x; s.y += p.y; s.z += p.z; s.w += p.w;
  }
  *reinterpret_cast<float4*>(out + i4) = s;
}

// ---------------- persistent LSTM: reg f16 weights, fused split-K reduce, depth-2 P prefetch ----------------
template <int H2C, int BLK, int Z>
__global__ __launch_bounds__(BLK)
void lstm_kernel(const float* __restrict__ P, const float* __restrict__ bias,
                 const half2_t* __restrict__ Wp, float* __restrict__ out,
                 int S, int MN){
  constexpr int H = 2 * H2C;
  constexpr int H4 = 4 * H;
  __shared__ _Float16 __attribute__((aligned(16))) hsh[H];
  __shared__ float gv[H4];
  const int b = blockIdx.x, t = threadIdx.x;
  half2_t w[H2C];
  const half2_t* wp = Wp + t;
  #pragma unroll
  for (int j2 = 0; j2 < H2C; ++j2) w[j2] = wp[(size_t)j2 * H4];
  float cc = 0.f;
  if (t < H) hsh[t] = (_Float16)0.f;
  const float bval = bias[t];
  const size_t base = (size_t)b * S * H4 + t;
  float pv0[Z], pv1[Z];
  #pragma unroll
  for (int z = 0; z < Z; ++z) pv0[z] = P[(size_t)z * MN + base];
  #pragma unroll
  for (int z = 0; z < Z; ++z) pv1[z] = P[(size_t)z * MN + base + H4];
  __syncthreads();
  const half2_t* hp = reinterpret_cast<const half2_t*>(hsh);
  for (int s = 0; s < S; ++s){
    float pvn[Z];
    if (s + 2 < S){
      size_t o2 = base + (size_t)(s + 2) * H4;
      #pragma unroll
      for (int z = 0; z < Z; ++z) pvn[z] = P[(size_t)z * MN + o2];
    }
    float a0 = bval, a1 = 0.f, a2 = 0.f, a3 = 0.f;
    float a4 = 0.f, a5 = 0.f, a6 = 0.f, a7 = 0.f;
    #pragma unroll
    for (int z = 0; z < Z; ++z) a0 += pv0[z];
    #pragma unroll
    for (int j2 = 0; j2 < H2C; j2 += 8){
      a0 = dot2(w[j2],     hp[j2],     a0);
      a1 = dot2(w[j2 + 1], hp[j2 + 1], a1);
      a2 = dot2(w[j2 + 2], hp[j2 + 2], a2);
      a3 = dot2(w[j2 + 3], hp[j2 + 3], a3);
      a4 = dot2(w[j2 + 4], hp[j2 + 4], a4);
      a5 = dot2(w[j2 + 5], hp[j2 + 5], a5);
      a6 = dot2(w[j2 + 6], hp[j2 + 6], a6);
      a7 = dot2(w[j2 + 7], hp[j2 + 7], a7);
    }
    gv[t] = ((a0 + a1) + (a2 + a3)) + ((a4 + a5) + (a6 + a7));
    __syncthreads();
    if (t < H){
      float ig = sigf(gv[t]);
      float fg = sigf(gv[H + t]);
      float gg = tanhf(gv[2 * H + t]);
      float og = sigf(gv[3 * H + t]);
      cc = fg * cc + ig * gg;
      float hh = og * tanhf(cc);
      hsh[t] = (_Float16)hh;
      out[((size_t)b * S + s) * H + t] = hh;
    }
    __syncthreads();
    #pragma unroll
    for (int z = 0; z < Z; ++z){ pv0[z] = pv1[z]; pv1[z] = pvn[z]; }
  }
}

// ---------------- bnseg apply + transpose to g2in[nm][s][v][c] (coalesced) ----------------
__global__ void bnseg_to_g2in_kernel(const float* __restrict__ lout, const float* __restrict__ sum,
                                     const float* __restrict__ sumsq, const float* __restrict__ g,
                                     const float* __restrict__ bb, float* __restrict__ g2in,
                                     int B, int S, int H, int cnt){
  int idx = blockIdx.x * blockDim.x + threadIdx.x;
  int total = B * S * H;
  if (idx >= total) return;
  int hh = idx % H;
  int s = (idx / H) % S;
  int b = idx / (H * S);
  float mean = sum[s] / cnt;
  float rstd = rsqrtf(sumsq[s] / cnt - mean * mean + 1e-5f);
  float val = (lout[idx] - mean) * rstd * g[s] + bb[s];
  int nm = b / 25, v = b % 25;
  g2in[(((size_t)(nm * S + s) * 25 + v) * H) + hh] = val;
}

// ---------------- support2 (coalesced both sides): A2mat[(nm*S+s)*25+v][k*96+c], stride 1280 ----------------
__global__ void support2_kernel(const float* __restrict__ A, const float* __restrict__ g2in,
                                bf16_t* __restrict__ A2mat, int NM, int C1, int S){
  int idx = blockIdx.x * blockDim.x + threadIdx.x;
  int total = NM * S * 25 * 13 * 96;
  if (idx >= total) return;
  int c = idx % 96;
  int k = (idx / 96) % 13;
  int v = (idx / (96 * 13)) % 25;
  int rs = idx / (96 * 13 * 25);       // nm*S + s
  const float* gbase = g2in + ((size_t)rs * 25) * 96 + c;  // u stride 96
  const float* ar = A + (k * 25 + v) * 25;
  float acc = 0.f;
  #pragma unroll
  for (int u = 0; u < 25; ++u) acc += ar[u] * gbase[(size_t)u * 96];
  A2mat[((size_t)rs * 25 + v) * 1280 + k * 96 + c] = f2bf(acc);
}

// ---------------- bnseg2 (from sums) + global pool ----------------
__global__ void pool_kernel(const float* __restrict__ lout2, const float* __restrict__ sum,
                            const float* __restrict__ sumsq, const float* __restrict__ g,
                            const float* __restrict__ bb, float* __restrict__ pooled,
                            int S, int H, int scnt){
  int n = blockIdx.x / H;
  int o = blockIdx.x % H;
  float acc = 0.f;
  int cnt = 2 * 25 * S;
  for (int i = threadIdx.x; i < cnt; i += 64){
    int m = i / (25 * S);
    int r = i % (25 * S);
    int v = r / S;
    int s = r % S;
    int b = (n * 2 + m) * 25 + v;
    float val = lout2[((size_t)b * S + s) * H + o];
    float mean = sum[s] / scnt;
    float rstd = rsqrtf(sumsq[s] / scnt - mean * mean + 1e-5f);
    val = (val - mean) * rstd * g[s] + bb[s];
    acc += val;
  }
  for (int off = 32; off; off >>= 1) acc += __shfl_down(acc, off);
  if (threadIdx.x == 0) pooled[n * H + o] = acc / cnt;
}

// ---------------- final FC ----------------
__global__ void fc_kernel(const float* __restrict__ pooled, const float* __restrict__ fcW,
                          const float* __restrict__ fcb, float* __restrict__ outp){
  int idx = blockIdx.x * blockDim.x + threadIdx.x;
  if (idx >= 120) return;
  int n = idx / 60, cls = idx % 60;
  float acc = fcb[cls];
  for (int o = 0; o < 192; ++o) acc += pooled[n * 192 + o] * fcW[cls * 192 + o];
  outp[idx] = acc;
}

// ---------------- host: replicate np.linspace + python round (ties-to-even) ----------------
static void make_segs(int T, int S, SegTable& tab, int& L){
  double step = (double)(T - 1) / (double)S;
  long long tv[51];
  for (int i = 0; i <= S; ++i){
    double v = 1.0 + step * (double)i;
    tv[i] = llrint(v);
  }
  L = 0;
  for (int s = 0; s < S; ++s){
    tab.st[s] = (int)tv[s] - 1;
    tab.en[s] = (int)tv[s + 1] - 1;
    int len = tab.en[s] - tab.st[s] + 1;
    if (len > L) L = len;
  }
  for (int s = S; s < 50; ++s){ tab.st[s] = 0; tab.en[s] = 0; }
  if (L > 4) L = 4;
}

extern "C" void kernel_launch(void* const* d_in, const int* in_sizes, int n_in,
                              void* d_out, int out_size, void* d_ws, size_t ws_size,
                              hipStream_t stream){
  const float* x         = (const float*)d_in[0];
  const float* data_bn_g = (const float*)d_in[2];
  const float* data_bn_b = (const float*)d_in[3];
  const float* A_powers1 = (const float*)d_in[4];
  const float* A_res1    = (const float*)d_in[5];
  const float* W1        = (const float*)d_in[6];
  const float* b1        = (const float*)d_in[7];
  const float* bn1_g     = (const float*)d_in[8];
  const float* bn1_b     = (const float*)d_in[9];
  const float* Wih1      = (const float*)d_in[10];
  const float* Whh1      = (const float*)d_in[11];
  const float* bih1      = (const float*)d_in[12];
  const float* bhh1      = (const float*)d_in[13];
  const float* bnseg1_g  = (const float*)d_in[14];
  const float* bnseg1_b  = (const float*)d_in[15];
  const float* A_powers2 = (const float*)d_in[16];
  const float* A_res2    = (const float*)d_in[17];
  const float* W2        = (const float*)d_in[18];
  const float* b2        = (const float*)d_in[19];
  const float* bn2_g     = (const float*)d_in[20];
  const float* bn2_b     = (const float*)d_in[21];
  const float* Wih2      = (const float*)d_in[22];
  const float* Whh2      = (const float*)d_in[23];
  const float* bih2      = (const float*)d_in[24];
  const float* bhh2      = (const float*)d_in[25];
  const float* bnseg2_g  = (const float*)d_in[26];
  const float* bnseg2_b  = (const float*)d_in[27];
  const float* fcW       = (const float*)d_in[28];
  const float* fcb       = (const float*)d_in[29];
  float* out = (float*)d_out;

  const int N = 2, C = 3, T = 100, V = 25, M = 2, NM = 4;
  const int K = 13, C1 = 96, C2 = 192;
  const int S1 = 50, S2 = 30;
  const int B = 100;
  const int IN1 = 4752, IN2 = 18720;
  const int IN1P = 4800, IN2P = 18752;  // K padded to %64
  const int P1 = 4560, P2 = 18336;
  const int KG2 = 1248, KG2P = 1280;
  const int Z1 = 5, Z2 = 6, ZG = 4;

  size_t off = 0;
  char* base = (char*)d_ws;
  auto alloc = [&](size_t nbytes) -> void* {
    off = (off + 255) & ~(size_t)255;
    void* p = base + off;
    off += nbytes;
    return p;
  };
  float* A1full = (float*)alloc(325 * 25 * 4);
  float* A2full = (float*)alloc(325 * 25 * 4);
  float* h1     = (float*)alloc((size_t)NM * C * T * V * 4);
  float* sup1   = (float*)alloc((size_t)NM * C * T * 325 * 4);
  float* y1mat  = (float*)alloc((size_t)NM * T * V * C1 * 4);
  float* stats  = (float*)alloc(736 * 4);
  float* st1a = stats, *st1b = stats + 96;
  float* sg1a = stats + 192, *sg1b = stats + 242;
  float* st2a = stats + 292, *st2b = stats + 484;
  float* sg2a = stats + 676, *sg2b = stats + 706;
  float* xseq1  = (float*)alloc((size_t)B * T * C1 * 4);
  float* l1out  = (float*)alloc((size_t)B * S1 * C1 * 4);
  float* g2in   = (float*)alloc((size_t)NM * S1 * V * C1 * 4);
  bf16_t* A2mat = (bf16_t*)alloc((size_t)NM * S1 * V * KG2P * 2);
  float* y2mat  = (float*)alloc((size_t)NM * S1 * V * C2 * 4);
  float* xseq2  = (float*)alloc((size_t)B * S1 * C2 * 4);
  float* l2out  = (float*)alloc((size_t)B * S2 * C2 * 4);
  float* pooled = (float*)alloc(2 * C2 * 4);
  float* bias1  = (float*)alloc(4 * C1 * 4);
  float* bias2  = (float*)alloc(4 * C2 * 4);
  half2_t* Wp1  = (half2_t*)alloc((size_t)(C1 / 2) * 4 * C1 * 4);
  half2_t* Wp2  = (half2_t*)alloc((size_t)(C2 / 2) * 4 * C2 * 4);
  bf16_t* Wih1b = (bf16_t*)alloc((size_t)4 * C1 * IN1P * 2);
  bf16_t* Wih2b = (bf16_t*)alloc((size_t)4 * C2 * IN2P * 2);
  bf16_t* W2b   = (bf16_t*)alloc((size_t)C2 * KG2P * 2);
  unsigned short* lut1 = (unsigned short*)alloc((size_t)P1 * 2);
  unsigned short* lut2 = (unsigned short*)alloc((size_t)P2 * 2);
  size_t pmax = (size_t)Z2 * 3000 * 768;
  {
    size_t p1s = (size_t)Z1 * 5000 * 384; if (p1s > pmax) pmax = p1s;
    size_t pgs = (size_t)ZG * 5000 * 192; if (pgs > pmax) pmax = pgs;
  }
  float* Pbuf = (float*)alloc(pmax * 4);
  bf16_t* feats = (bf16_t*)alloc((size_t)B * S2 * IN2P * 2);
  (void)ws_size; (void)in_sizes; (void)n_in; (void)out_size;

  // one prep dispatch: adds, whh packs, LUTs, stat zeros, A2mat K-pad
  prep_misc<<<625, 256, 0, stream>>>(A_powers1, A_res1, A1full, A_powers2, A_res2, A2full,
                                     bih1, bhh1, bias1, bih2, bhh2, bias2,
                                     Whh1, Wp1, Whh2, Wp2, lut1, lut2, stats, A2mat);
  {
    int c1 = 4 * C1 * (IN1P / 8);         // 230400
    int c2 = 4 * C2 * (IN2P / 8);         // 1800192
    int c3 = C2 * (KG2P / 8);             // 30720
    int tot = c1 + c2 + c3;
    f2bf_pad8_3<<<(tot + 255) / 256, 256, 0, stream>>>(Wih1, Wih1b, IN1, IN1P, c1,
                                                       Wih2, Wih2b, IN2, IN2P, c2,
                                                       W2, W2b, KG2, KG2P, c3);
  }

  // stage 0: data BN
  data_bn_kernel<<<M * V * C, 64, 0, stream>>>(x, data_bn_g, data_bn_b, h1, N, C, T, V, M);

  // stage 1: GCN1
  int tot_sup1 = NM * C * T * 325;
  support1_kernel<<<(tot_sup1 + 255) / 256, 256, 0, stream>>>(A1full, h1, sup1, tot_sup1);
  int tot_y1 = NM * T * 25 * C1;
  gcn1_out_kernel<<<(tot_y1 + 255) / 256, 256, 0, stream>>>(sup1, W1, b1, y1mat, NM, T);
  colstats_atomic<<<256, C1, 0, stream>>>(y1mat, NM * T * 25, st1a, st1b);
  bn_relu_seq_kernel<<<(tot_y1 + 255) / 256, 256, 0, stream>>>(y1mat, st1a, st1b, bn1_g, bn1_b,
                                                               xseq1, NM, T, C1, NM * T * 25);

  // stage 1: logsig-rnn
  SegTable seg1, seg2; int L1, L2;
  make_segs(T, S1, seg1, L1);
  make_segs(S1, S2, seg2, L2);

  feats_kernel<<<B * S1, 256, 0, stream>>>(xseq1, feats, seg1, (const unsigned int*)lut1,
                                           T, C1, S1, L1, P1, IN1P);
  {
    int Mm = B * S1, Nn = 4 * C1;
    dim3 g((Mm + 127) / 128, (Nn + 127) / 128, Z1);
    gemm_mfma_nt_split<<<g, 256, 0, stream>>>(feats, Wih1b, Pbuf, Mm, Nn, IN1P);
    lstm_kernel<48, 384, Z1><<<B, 384, 0, stream>>>(Pbuf, bias1, Wp1, l1out, S1, Mm * Nn);
  }
  segstats_atomic<<<256, C1, 0, stream>>>(l1out, B * S1, S1, sg1a, sg1b);
  int tot_bn1 = B * S1 * C1;
  bnseg_to_g2in_kernel<<<(tot_bn1 + 255) / 256, 256, 0, stream>>>(l1out, sg1a, sg1b, bnseg1_g,
                                                                  bnseg1_b, g2in, B, S1, C1, B * C1);

  // stage 2: GCN2 (MFMA, split-K)
  int tot_sup2 = NM * S1 * 25 * 13 * 96;
  support2_kernel<<<(tot_sup2 + 255) / 256, 256, 0, stream>>>(A2full, g2in, A2mat, NM, C1, S1);
  {
    int Mm = NM * S1 * 25, Nn = C2;
    dim3 g((Mm + 127) / 128, (Nn + 127) / 128, ZG);
    gemm_mfma_nt_split<<<g, 256, 0, stream>>>(A2mat, W2b, Pbuf, Mm, Nn, KG2P);
    int MN = Mm * Nn;
    reduce_split_bias<<<(MN / 4 + 255) / 256, 256, 0, stream>>>(Pbuf, b2, y2mat, MN, Nn, ZG);
  }
  colstats_atomic<<<256, C2, 0, stream>>>(y2mat, NM * S1 * 25, st2a, st2b);
  int tot_y2 = NM * S1 * 25 * C2;
  bn_relu_seq_kernel<<<(tot_y2 + 255) / 256, 256, 0, stream>>>(y2mat, st2a, st2b, bn2_g, bn2_b,
                                                               xseq2, NM, S1, C2, NM * S1 * 25);

  // stage 2: logsig-rnn
  feats_kernel<<<B * S2, 256, 0, stream>>>(xseq2, feats, seg2, (const unsigned int*)lut2,
                                           S1, C2, S2, L2, P2, IN2P);
  {
    int Mm = B * S2, Nn = 4 * C2;
    dim3 g((Mm + 127) / 128, (Nn + 127) / 128, Z2);
    gemm_mfma_nt_split<<<g, 256, 0, stream>>>(feats, Wih2b, Pbuf, Mm, Nn, IN2P);
    lstm_kernel<96, 768, Z2><<<B, 768, 0, stream>>>(Pbuf, bias2, Wp2, l2out, S2, Mm * Nn);
  }
  segstats_atomic<<<256, C2, 0, stream>>>(l2out, B * S2, S2, sg2a, sg2b);

  // pool + fc
  pool_kernel<<<2 * C2, 64, 0, stream>>>(l2out, sg2a, sg2b, bnseg2_g, bnseg2_b, pooled, S2, C2, B * C2);
  fc_kernel<<<1, 128, 0, stream>>>(pooled, fcW, fcb, out);
}